// Round 1
// baseline (966.326 us; speedup 1.0000x reference)
//
#include <hip/hip_runtime.h>
#include <hip/hip_bf16.h>

typedef __attribute__((ext_vector_type(8))) short short8;
typedef __attribute__((ext_vector_type(4))) float f32x4;
typedef __attribute__((ext_vector_type(4))) unsigned short u16x4;
typedef unsigned short u16;
typedef unsigned long long u64;

#define NB 16
#define NS 512
#define ND 512
#define NH 8
#define NT 8
#define NDK 64
#define NN (NB*NS)
#define ATT_SCALE 0.125f
#define BM 128
#define BN 128
#define BKK 64

__device__ __forceinline__ u16 f2bf(float f) {
    __hip_bfloat16 h = __float2bfloat16(f);
    return *reinterpret_cast<u16*>(&h);
}

// ---------------- bucketize tokens by type ----------------
__global__ __launch_bounds__(256) void bucketize(
    const int* __restrict__ xty, int* __restrict__ perm, int* __restrict__ typeoff,
    int* __restrict__ tile_type, int* __restrict__ tile_row0, int* __restrict__ ntiles)
{
    __shared__ int cnt[NT], off[NT + 1], cur[NT];
    int tid = threadIdx.x;
    if (tid < NT) cnt[tid] = 0;
    __syncthreads();
    for (int n = tid; n < NN; n += 256) atomicAdd(&cnt[xty[n]], 1);
    __syncthreads();
    if (tid == 0) {
        int acc = 0, nt = 0;
        for (int t = 0; t < NT; ++t) {
            off[t] = acc;
            for (int r = 0; r < cnt[t]; r += BM) { tile_type[nt] = t; tile_row0[nt] = acc + r; ++nt; }
            acc += cnt[t];
        }
        off[NT] = acc;
        *ntiles = nt;
        for (int t = 0; t <= NT; ++t) typeoff[t] = off[t];
    }
    __syncthreads();
    if (tid < NT) cur[tid] = off[tid];
    __syncthreads();
    for (int n = tid; n < NN; n += 256) {
        int t = xty[n];
        int p = atomicAdd(&cur[t], 1);
        perm[p] = n;
    }
}

// ---------------- x f32 -> bf16 ----------------
__global__ __launch_bounds__(256) void cvt_x(const float* __restrict__ x, u16* __restrict__ xb)
{
    int i = blockIdx.x * 256 + threadIdx.x;       // one float4 each; grid covers exactly N*D/4
    float4 v = reinterpret_cast<const float4*>(x)[i];
    u16x4 o;
    o.x = f2bf(v.x); o.y = f2bf(v.y); o.z = f2bf(v.z); o.w = f2bf(v.w);
    reinterpret_cast<u16x4*>(xb)[i] = o;
}

// ---------------- W [t][d][h] f32 -> Wt [t][h][d] bf16 (transpose+convert) ----------------
__global__ __launch_bounds__(256) void cvt_w(
    const float* __restrict__ Wq, const float* __restrict__ Wk,
    const float* __restrict__ Wv, const float* __restrict__ Wa,
    u16* __restrict__ Wqt, u16* __restrict__ Wkt, u16* __restrict__ Wvt, u16* __restrict__ Wat)
{
    int arr = blockIdx.z >> 3, t = blockIdx.z & 7;
    const float* W = (arr == 0 ? Wq : arr == 1 ? Wk : arr == 2 ? Wv : Wa) + ((size_t)t << 18);
    u16* O = (arr == 0 ? Wqt : arr == 1 ? Wkt : arr == 2 ? Wvt : Wat) + ((size_t)t << 18);
    int d0 = blockIdx.x * 64, h0 = blockIdx.y * 64;
    __shared__ __align__(16) float tile[64][68];
    int tx = threadIdx.x & 15, ty = threadIdx.x >> 4;
    #pragma unroll
    for (int i = 0; i < 4; ++i) {
        int r = ty + i * 16;
        float4 v = *reinterpret_cast<const float4*>(&W[(size_t)(d0 + r) * ND + h0 + tx * 4]);
        *reinterpret_cast<float4*>(&tile[r][tx * 4]) = v;
    }
    __syncthreads();
    #pragma unroll
    for (int i = 0; i < 4; ++i) {
        int r = ty + i * 16;                      // output row (h)
        u16x4 o;
        o.x = f2bf(tile[tx * 4 + 0][r]);
        o.y = f2bf(tile[tx * 4 + 1][r]);
        o.z = f2bf(tile[tx * 4 + 2][r]);
        o.w = f2bf(tile[tx * 4 + 3][r]);
        *reinterpret_cast<u16x4*>(&O[(size_t)(h0 + r) * ND + d0 + tx * 4]) = o;
    }
}

// ---------------- bitpack mask: 64 keys -> one u64 ----------------
__global__ __launch_bounds__(256) void pack_mask(const int* __restrict__ mask, u64* __restrict__ maskb)
{
    int i = blockIdx.x * 256 + threadIdx.x;
    int v = mask[i];
    u64 bal = __ballot(v != 0);
    if ((threadIdx.x & 63) == 0) maskb[i >> 6] = bal;
}

// ---------------- grouped GEMM: q/k/v = xb @ W[t]^T(pre-transposed) + b ----------------
__global__ __launch_bounds__(256) void qkv_gemm(
    const u16* __restrict__ xb,
    const u16* __restrict__ Wqt, const u16* __restrict__ Wkt, const u16* __restrict__ Wvt,
    const float* __restrict__ bq, const float* __restrict__ bk, const float* __restrict__ bv,
    const int* __restrict__ perm, const int* __restrict__ typeoff,
    const int* __restrict__ tile_type, const int* __restrict__ tile_row0, const int* __restrict__ ntiles,
    float* __restrict__ qf, float* __restrict__ kf, float* __restrict__ vf)
{
    if (blockIdx.x >= *ntiles) return;
    int t = tile_type[blockIdx.x];
    int row0 = tile_row0[blockIdx.x];
    int rows = typeoff[t + 1] - row0; if (rows > BM) rows = BM;
    int proj = blockIdx.y >> 2;
    int col0 = (blockIdx.y & 3) * BN;
    const u16* W = (proj == 0 ? Wqt : proj == 1 ? Wkt : Wvt) + ((size_t)t << 18);
    const float* bias = (proj == 0 ? bq : proj == 1 ? bk : bv) + (t << 9);
    float* outp = (proj == 0 ? qf : proj == 1 ? kf : vf);

    __shared__ __align__(16) u16 As[BM][BKK];
    __shared__ __align__(16) u16 Bs[BN][BKK];
    __shared__ int stok[BM];

    int tid = threadIdx.x;
    if (tid < BM) stok[tid] = perm[row0 + (tid < rows ? tid : 0)];
    __syncthreads();

    int lane = tid & 63, wave = tid >> 6;
    int wr = wave >> 1, wc = wave & 1;
    int fr = lane & 15, fk = (lane >> 4) << 3;

    f32x4 acc[4][4] = {};

    for (int k0 = 0; k0 < ND; k0 += BKK) {
        #pragma unroll
        for (int c = 0; c < 4; ++c) {
            int idx = c * 256 + tid;
            int r = idx >> 3, cc = (idx & 7) << 3;
            *reinterpret_cast<short8*>(&As[r][cc]) =
                *reinterpret_cast<const short8*>(xb + ((size_t)stok[r] << 9) + k0 + cc);
            *reinterpret_cast<short8*>(&Bs[r][cc]) =
                *reinterpret_cast<const short8*>(W + ((size_t)(col0 + r) << 9) + k0 + cc);
        }
        __syncthreads();
        #pragma unroll
        for (int ks = 0; ks < 2; ++ks) {
            short8 af[4], bfr[4];
            #pragma unroll
            for (int m = 0; m < 4; ++m)
                af[m] = *reinterpret_cast<const short8*>(&As[wr * 64 + m * 16 + fr][ks * 32 + fk]);
            #pragma unroll
            for (int n = 0; n < 4; ++n)
                bfr[n] = *reinterpret_cast<const short8*>(&Bs[wc * 64 + n * 16 + fr][ks * 32 + fk]);
            #pragma unroll
            for (int m = 0; m < 4; ++m)
                #pragma unroll
                for (int n = 0; n < 4; ++n)
                    acc[m][n] = __builtin_amdgcn_mfma_f32_16x16x32_bf16(af[m], bfr[n], acc[m][n], 0, 0, 0);
        }
        __syncthreads();
    }

    int rbase = (lane >> 4) << 2;
    #pragma unroll
    for (int n = 0; n < 4; ++n) {
        int c = col0 + wc * 64 + n * 16 + fr;     // [0,512)
        float bv_ = bias[c];
        int h = c >> 6, dk = c & 63;
        #pragma unroll
        for (int m = 0; m < 4; ++m) {
            #pragma unroll
            for (int i = 0; i < 4; ++i) {
                int r = wr * 64 + m * 16 + rbase + i;
                if (r < rows) {
                    int tok = stok[r];
                    int b = tok >> 9, s = tok & 511;
                    size_t off = (size_t)((b * NH + h) * NS + s) * NDK + dk;
                    outp[off] = acc[m][n][i] + bv_;
                }
            }
        }
    }
}

// ---------------- flash attention, VALU f32: 64 q-rows/block, 16 per wave ----------------
__global__ __launch_bounds__(256) void attn(
    const float* __restrict__ qf, const float* __restrict__ kf, const float* __restrict__ vf,
    const u64* __restrict__ maskb, u16* __restrict__ attb)
{
    int bh = blockIdx.y;
    int b = bh >> 3, h = bh & 7;
    int q0 = blockIdx.x * 64;
    int tid = threadIdx.x, lane = tid & 63, w = tid >> 6;

    __shared__ __align__(16) float sQ[64 * 64];   // [row][dk]
    __shared__ __align__(16) float sK[64 * 64];   // [key][d4 xor-swizzled]
    __shared__ __align__(16) float sP[4 * 16 * 64];

    const float* Qg = qf + ((size_t)bh * NS + q0) * NDK;
    #pragma unroll
    for (int c = 0; c < 4; ++c) {
        int idx = c * 256 + tid;
        reinterpret_cast<float4*>(sQ)[idx] = reinterpret_cast<const float4*>(Qg)[idx];
    }

    float mrun[16], lrun[16], oacc[16];
    #pragma unroll
    for (int r = 0; r < 16; ++r) { mrun[r] = -3.0e38f; lrun[r] = 0.f; oacc[r] = 0.f; }

    const float* Kg = kf + (size_t)bh * NS * NDK;
    const float* Vg = vf + (size_t)bh * NS * NDK;
    const u64* Mrow = maskb + ((size_t)(b << 9) + q0) * (NS / 64);

    for (int j = 0; j < 8; ++j) {
        __syncthreads();                           // prior readers of sK done (also orders sQ stage at j=0)
        #pragma unroll
        for (int c = 0; c < 4; ++c) {
            int idx = c * 256 + tid;
            int k = idx >> 4, d4 = idx & 15;
            float4 v = reinterpret_cast<const float4*>(Kg + ((size_t)(j * 64 + k) << 6))[d4];
            reinterpret_cast<float4*>(sK)[k * 16 + (d4 ^ (k & 15))] = v;
        }
        __syncthreads();

        float s[16];
        #pragma unroll
        for (int r = 0; r < 16; ++r) s[r] = 0.f;
        #pragma unroll
        for (int d4 = 0; d4 < 16; ++d4) {
            float4 kv = reinterpret_cast<const float4*>(sK)[lane * 16 + (d4 ^ (lane & 15))];
            #pragma unroll
            for (int r = 0; r < 16; ++r) {
                float4 qv = reinterpret_cast<const float4*>(sQ)[(w * 16 + r) * 16 + d4];
                s[r] += qv.x * kv.x + qv.y * kv.y + qv.z * kv.z + qv.w * kv.w;
            }
        }
        #pragma unroll
        for (int r = 0; r < 16; ++r) {
            u64 mw = Mrow[(size_t)(w * 16 + r) * 8 + j];
            bool keep = (mw >> lane) & 1ull;
            float sv = keep ? s[r] * ATT_SCALE : -1e9f;
            float mx = sv;
            #pragma unroll
            for (int off = 32; off; off >>= 1) mx = fmaxf(mx, __shfl_xor(mx, off));
            float nm = fmaxf(mrun[r], mx);
            float sc = __expf(mrun[r] - nm);
            float p = __expf(sv - nm);
            mrun[r] = nm;
            lrun[r] = lrun[r] * sc + p;            // per-lane partial; reduced at end
            oacc[r] *= sc;
            sP[(w * 16 + r) * 64 + lane] = p;
        }
        __syncthreads();                           // sP visible (safety; per-wave slices)
        #pragma unroll
        for (int k4 = 0; k4 < 16; ++k4) {
            int kk = j * 64 + k4 * 4;
            float v0 = Vg[((size_t)(kk + 0) << 6) + lane];
            float v1 = Vg[((size_t)(kk + 1) << 6) + lane];
            float v2 = Vg[((size_t)(kk + 2) << 6) + lane];
            float v3 = Vg[((size_t)(kk + 3) << 6) + lane];
            #pragma unroll
            for (int r = 0; r < 16; ++r) {
                float4 p4 = reinterpret_cast<const float4*>(sP)[(w * 16 + r) * 16 + k4];
                oacc[r] += p4.x * v0 + p4.y * v1 + p4.z * v2 + p4.w * v3;
            }
        }
    }
    #pragma unroll
    for (int r = 0; r < 16; ++r) {
        float ls = lrun[r];
        #pragma unroll
        for (int off = 32; off; off >>= 1) ls += __shfl_xor(ls, off);
        float o = oacc[r] / ls;
        int q = q0 + w * 16 + r;
        int n = (b << 9) + q;
        attb[((size_t)n << 9) + (h << 6) + lane] = f2bf(o);
    }
}

// ---------------- grouped out-proj GEMM + bias + residual ----------------
__global__ __launch_bounds__(256) void out_gemm(
    const u16* __restrict__ attb, const u16* __restrict__ Wat, const float* __restrict__ ba,
    const int* __restrict__ perm, const int* __restrict__ typeoff,
    const int* __restrict__ tile_type, const int* __restrict__ tile_row0, const int* __restrict__ ntiles,
    const float* __restrict__ x, float* __restrict__ hbuf)
{
    if (blockIdx.x >= *ntiles) return;
    int t = tile_type[blockIdx.x];
    int row0 = tile_row0[blockIdx.x];
    int rows = typeoff[t + 1] - row0; if (rows > BM) rows = BM;
    int col0 = blockIdx.y * BN;
    const u16* W = Wat + ((size_t)t << 18);
    const float* bias = ba + (t << 9);

    __shared__ __align__(16) u16 As[BM][BKK];
    __shared__ __align__(16) u16 Bs[BN][BKK];
    __shared__ int stok[BM];

    int tid = threadIdx.x;
    if (tid < BM) stok[tid] = perm[row0 + (tid < rows ? tid : 0)];
    __syncthreads();

    int lane = tid & 63, wave = tid >> 6;
    int wr = wave >> 1, wc = wave & 1;
    int fr = lane & 15, fk = (lane >> 4) << 3;

    f32x4 acc[4][4] = {};

    for (int k0 = 0; k0 < ND; k0 += BKK) {
        #pragma unroll
        for (int c = 0; c < 4; ++c) {
            int idx = c * 256 + tid;
            int r = idx >> 3, cc = (idx & 7) << 3;
            *reinterpret_cast<short8*>(&As[r][cc]) =
                *reinterpret_cast<const short8*>(attb + ((size_t)stok[r] << 9) + k0 + cc);
            *reinterpret_cast<short8*>(&Bs[r][cc]) =
                *reinterpret_cast<const short8*>(W + ((size_t)(col0 + r) << 9) + k0 + cc);
        }
        __syncthreads();
        #pragma unroll
        for (int ks = 0; ks < 2; ++ks) {
            short8 af[4], bfr[4];
            #pragma unroll
            for (int m = 0; m < 4; ++m)
                af[m] = *reinterpret_cast<const short8*>(&As[wr * 64 + m * 16 + fr][ks * 32 + fk]);
            #pragma unroll
            for (int n = 0; n < 4; ++n)
                bfr[n] = *reinterpret_cast<const short8*>(&Bs[wc * 64 + n * 16 + fr][ks * 32 + fk]);
            #pragma unroll
            for (int m = 0; m < 4; ++m)
                #pragma unroll
                for (int n = 0; n < 4; ++n)
                    acc[m][n] = __builtin_amdgcn_mfma_f32_16x16x32_bf16(af[m], bfr[n], acc[m][n], 0, 0, 0);
        }
        __syncthreads();
    }

    int rbase = (lane >> 4) << 2;
    #pragma unroll
    for (int n = 0; n < 4; ++n) {
        int c = col0 + wc * 64 + n * 16 + fr;
        float bv_ = bias[c];
        #pragma unroll
        for (int m = 0; m < 4; ++m) {
            #pragma unroll
            for (int i = 0; i < 4; ++i) {
                int r = wr * 64 + m * 16 + rbase + i;
                if (r < rows) {
                    int tok = stok[r];
                    size_t off = (size_t)tok * ND + c;
                    hbuf[off] = acc[m][n][i] + bv_ + x[off];
                }
            }
        }
    }
}

// ---------------- per-type LayerNorm ----------------
__global__ __launch_bounds__(256) void lnorm(
    const float* __restrict__ hbuf, const int* __restrict__ xty,
    const float* __restrict__ gamma, const float* __restrict__ beta, float* __restrict__ out)
{
    int row = blockIdx.x * 4 + (threadIdx.x >> 6);
    int lane = threadIdx.x & 63;
    const float4* h4 = reinterpret_cast<const float4*>(hbuf + (size_t)row * ND);
    float4 a = h4[lane * 2], b = h4[lane * 2 + 1];
    float sum = a.x + a.y + a.z + a.w + b.x + b.y + b.z + b.w;
    float sq = a.x * a.x + a.y * a.y + a.z * a.z + a.w * a.w
             + b.x * b.x + b.y * b.y + b.z * b.z + b.w * b.w;
    #pragma unroll
    for (int off = 32; off; off >>= 1) { sum += __shfl_xor(sum, off); sq += __shfl_xor(sq, off); }
    float mu = sum * (1.f / ND);
    float var = sq * (1.f / ND) - mu * mu;
    float is = rsqrtf(var + 1e-5f);
    int t = xty[row];
    const float4* g4 = reinterpret_cast<const float4*>(gamma + ((size_t)t << 9));
    const float4* be4 = reinterpret_cast<const float4*>(beta + ((size_t)t << 9));
    float4 g0 = g4[lane * 2], g1 = g4[lane * 2 + 1];
    float4 b0 = be4[lane * 2], b1 = be4[lane * 2 + 1];
    float4 o0, o1;
    o0.x = (a.x - mu) * is * g0.x + b0.x;
    o0.y = (a.y - mu) * is * g0.y + b0.y;
    o0.z = (a.z - mu) * is * g0.z + b0.z;
    o0.w = (a.w - mu) * is * g0.w + b0.w;
    o1.x = (b.x - mu) * is * g1.x + b1.x;
    o1.y = (b.y - mu) * is * g1.y + b1.y;
    o1.z = (b.z - mu) * is * g1.z + b1.z;
    o1.w = (b.w - mu) * is * g1.w + b1.w;
    float4* out4 = reinterpret_cast<float4*>(out + (size_t)row * ND);
    out4[lane * 2] = o0; out4[lane * 2 + 1] = o1;
}

extern "C" void kernel_launch(void* const* d_in, const int* in_sizes, int n_in,
                              void* d_out, int out_size, void* d_ws, size_t ws_size,
                              hipStream_t stream)
{
    const float* x     = (const float*)d_in[0];
    const int*   xty   = (const int*)d_in[1];
    const int*   mask  = (const int*)d_in[2];
    const float* Wq    = (const float*)d_in[3];
    const float* bq    = (const float*)d_in[4];
    const float* Wk    = (const float*)d_in[5];
    const float* bk    = (const float*)d_in[6];
    const float* Wv    = (const float*)d_in[7];
    const float* bv    = (const float*)d_in[8];
    const float* Wa    = (const float*)d_in[9];
    const float* ba    = (const float*)d_in[10];
    const float* gamma = (const float*)d_in[11];
    const float* beta  = (const float*)d_in[12];
    float* out = (float*)d_out;

    char* ws = (char*)d_ws;
    u16*   xb      = (u16*)(ws + 0);             //  8,388,608
    u16*   Wqt     = (u16*)(ws + 8388608);       //  4,194,304
    u16*   Wkt     = (u16*)(ws + 12582912);
    u16*   Wvt     = (u16*)(ws + 16777216);
    u16*   Wat     = (u16*)(ws + 20971520);
    float* qf      = (float*)(ws + 25165824);    // 16,777,216
    float* kf      = (float*)(ws + 41943040);
    float* vf      = (float*)(ws + 58720256);
    u16*   attb    = (u16*)(ws + 75497472);      //  8,388,608
    float* hbuf    = (float*)(ws + 83886080);    // 16,777,216
    u64*   maskb   = (u64*)(ws + 100663296);     //    524,288
    int*   perm    = (int*)(ws + 101187584);     //     32,768
    int*   typeoff = (int*)(ws + 101220352);
    int*   ttile   = (int*)(ws + 101220416);
    int*   trow    = (int*)(ws + 101220736);
    int*   ntiles  = (int*)(ws + 101221056);

    bucketize<<<dim3(1), dim3(256), 0, stream>>>(xty, perm, typeoff, ttile, trow, ntiles);
    cvt_x<<<dim3(4096), dim3(256), 0, stream>>>(x, xb);
    cvt_w<<<dim3(8, 8, 32), dim3(256), 0, stream>>>(Wq, Wk, Wv, Wa, Wqt, Wkt, Wvt, Wat);
    pack_mask<<<dim3(16384), dim3(256), 0, stream>>>(mask, maskb);
    qkv_gemm<<<dim3(72, 12), dim3(256), 0, stream>>>(xb, Wqt, Wkt, Wvt, bq, bk, bv,
                                                     perm, typeoff, ttile, trow, ntiles, qf, kf, vf);
    attn<<<dim3(8, 128), dim3(256), 0, stream>>>(qf, kf, vf, maskb, attb);
    out_gemm<<<dim3(72, 4), dim3(256), 0, stream>>>(attb, Wat, ba,
                                                    perm, typeoff, ttile, trow, ntiles, x, hbuf);
    lnorm<<<dim3(2048), dim3(256), 0, stream>>>(hbuf, xty, gamma, beta, out);
}

// Round 2
// 299.260 us; speedup vs baseline: 3.2290x; 3.2290x over previous
//
#include <hip/hip_runtime.h>
#include <hip/hip_bf16.h>

typedef __attribute__((ext_vector_type(8))) short short8;
typedef __attribute__((ext_vector_type(4))) float f32x4;
typedef __attribute__((ext_vector_type(4))) unsigned short u16x4;
typedef unsigned short u16;
typedef unsigned long long u64;

#define NB 16
#define NS 512
#define ND 512
#define NH 8
#define NT 8
#define NDK 64
#define NN (NB*NS)
#define SCALE_LOG2E 0.18033688011112042f   // (1/sqrt(64)) * log2(e)
#define BM 128
#define BN 128
#define BKK 64

__device__ __forceinline__ u16 f2bf(float f) {
    __hip_bfloat16 h = __float2bfloat16(f);
    return *reinterpret_cast<u16*>(&h);
}

// ---------------- bucketize tokens by type ----------------
__global__ __launch_bounds__(256) void bucketize(
    const int* __restrict__ xty, int* __restrict__ perm, int* __restrict__ typeoff,
    int* __restrict__ tile_type, int* __restrict__ tile_row0, int* __restrict__ ntiles)
{
    __shared__ int cnt[NT], off[NT + 1], cur[NT];
    int tid = threadIdx.x;
    if (tid < NT) cnt[tid] = 0;
    __syncthreads();
    for (int n = tid; n < NN; n += 256) atomicAdd(&cnt[xty[n]], 1);
    __syncthreads();
    if (tid == 0) {
        int acc = 0, nt = 0;
        for (int t = 0; t < NT; ++t) {
            off[t] = acc;
            for (int r = 0; r < cnt[t]; r += BM) { tile_type[nt] = t; tile_row0[nt] = acc + r; ++nt; }
            acc += cnt[t];
        }
        off[NT] = acc;
        *ntiles = nt;
        for (int t = 0; t <= NT; ++t) typeoff[t] = off[t];
    }
    __syncthreads();
    if (tid < NT) cur[tid] = off[tid];
    __syncthreads();
    for (int n = tid; n < NN; n += 256) {
        int t = xty[n];
        int p = atomicAdd(&cur[t], 1);
        perm[p] = n;
    }
}

// ---------------- x f32 -> bf16 ----------------
__global__ __launch_bounds__(256) void cvt_x(const float* __restrict__ x, u16* __restrict__ xb)
{
    int i = blockIdx.x * 256 + threadIdx.x;
    float4 v = reinterpret_cast<const float4*>(x)[i];
    u16x4 o;
    o.x = f2bf(v.x); o.y = f2bf(v.y); o.z = f2bf(v.z); o.w = f2bf(v.w);
    reinterpret_cast<u16x4*>(xb)[i] = o;
}

// ---------------- W [t][d][h] f32 -> Wt [t][h][d] bf16 (transpose+convert) ----------------
__global__ __launch_bounds__(256) void cvt_w(
    const float* __restrict__ Wq, const float* __restrict__ Wk,
    const float* __restrict__ Wv, const float* __restrict__ Wa,
    u16* __restrict__ Wqt, u16* __restrict__ Wkt, u16* __restrict__ Wvt, u16* __restrict__ Wat)
{
    int arr = blockIdx.z >> 3, t = blockIdx.z & 7;
    const float* W = (arr == 0 ? Wq : arr == 1 ? Wk : arr == 2 ? Wv : Wa) + ((size_t)t << 18);
    u16* O = (arr == 0 ? Wqt : arr == 1 ? Wkt : arr == 2 ? Wvt : Wat) + ((size_t)t << 18);
    int d0 = blockIdx.x * 64, h0 = blockIdx.y * 64;
    __shared__ __align__(16) float tile[64][68];
    int tx = threadIdx.x & 15, ty = threadIdx.x >> 4;
    #pragma unroll
    for (int i = 0; i < 4; ++i) {
        int r = ty + i * 16;
        float4 v = *reinterpret_cast<const float4*>(&W[(size_t)(d0 + r) * ND + h0 + tx * 4]);
        *reinterpret_cast<float4*>(&tile[r][tx * 4]) = v;
    }
    __syncthreads();
    #pragma unroll
    for (int i = 0; i < 4; ++i) {
        int r = ty + i * 16;
        u16x4 o;
        o.x = f2bf(tile[tx * 4 + 0][r]);
        o.y = f2bf(tile[tx * 4 + 1][r]);
        o.z = f2bf(tile[tx * 4 + 2][r]);
        o.w = f2bf(tile[tx * 4 + 3][r]);
        *reinterpret_cast<u16x4*>(&O[(size_t)(h0 + r) * ND + d0 + tx * 4]) = o;
    }
}

// ---------------- bitpack mask: 64 keys -> one u64 ----------------
__global__ __launch_bounds__(256) void pack_mask(const int* __restrict__ mask, u64* __restrict__ maskb)
{
    int i = blockIdx.x * 256 + threadIdx.x;
    int v = mask[i];
    u64 bal = __ballot(v != 0);
    if ((threadIdx.x & 63) == 0) maskb[i >> 6] = bal;
}

// ---------------- grouped GEMM: q/k/v = xb @ W[t]^T + b ; bf16 out, V transposed ----------------
__global__ __launch_bounds__(256) void qkv_gemm(
    const u16* __restrict__ xb,
    const u16* __restrict__ Wqt, const u16* __restrict__ Wkt, const u16* __restrict__ Wvt,
    const float* __restrict__ bq, const float* __restrict__ bk, const float* __restrict__ bv,
    const int* __restrict__ perm, const int* __restrict__ typeoff,
    const int* __restrict__ tile_type, const int* __restrict__ tile_row0, const int* __restrict__ ntiles,
    u16* __restrict__ qb, u16* __restrict__ kbf, u16* __restrict__ vtb)
{
    if (blockIdx.x >= *ntiles) return;
    int t = tile_type[blockIdx.x];
    int row0 = tile_row0[blockIdx.x];
    int rows = typeoff[t + 1] - row0; if (rows > BM) rows = BM;
    int proj = blockIdx.y >> 2;
    int col0 = (blockIdx.y & 3) * BN;
    const u16* W = (proj == 0 ? Wqt : proj == 1 ? Wkt : Wvt) + ((size_t)t << 18);
    const float* bias = (proj == 0 ? bq : proj == 1 ? bk : bv) + (t << 9);

    __shared__ __align__(16) u16 As[BM][BKK];
    __shared__ __align__(16) u16 Bs[BN][BKK];
    __shared__ int stok[BM];

    int tid = threadIdx.x;
    if (tid < BM) stok[tid] = perm[row0 + (tid < rows ? tid : 0)];
    __syncthreads();

    int lane = tid & 63, wave = tid >> 6;
    int wr = wave >> 1, wc = wave & 1;
    int fr = lane & 15, fk = (lane >> 4) << 3;

    f32x4 acc[4][4] = {};

    for (int k0 = 0; k0 < ND; k0 += BKK) {
        #pragma unroll
        for (int c = 0; c < 4; ++c) {
            int idx = c * 256 + tid;
            int r = idx >> 3, cc = (idx & 7) << 3;
            *reinterpret_cast<short8*>(&As[r][cc]) =
                *reinterpret_cast<const short8*>(xb + ((size_t)stok[r] << 9) + k0 + cc);
            *reinterpret_cast<short8*>(&Bs[r][cc]) =
                *reinterpret_cast<const short8*>(W + ((size_t)(col0 + r) << 9) + k0 + cc);
        }
        __syncthreads();
        #pragma unroll
        for (int ks = 0; ks < 2; ++ks) {
            short8 af[4], bfr[4];
            #pragma unroll
            for (int m = 0; m < 4; ++m)
                af[m] = *reinterpret_cast<const short8*>(&As[wr * 64 + m * 16 + fr][ks * 32 + fk]);
            #pragma unroll
            for (int n = 0; n < 4; ++n)
                bfr[n] = *reinterpret_cast<const short8*>(&Bs[wc * 64 + n * 16 + fr][ks * 32 + fk]);
            #pragma unroll
            for (int m = 0; m < 4; ++m)
                #pragma unroll
                for (int n = 0; n < 4; ++n)
                    acc[m][n] = __builtin_amdgcn_mfma_f32_16x16x32_bf16(af[m], bfr[n], acc[m][n], 0, 0, 0);
        }
        __syncthreads();
    }

    int rbase = (lane >> 4) << 2;
    #pragma unroll
    for (int n = 0; n < 4; ++n) {
        int c = col0 + wc * 64 + n * 16 + fr;     // [0,512)
        float bv_ = bias[c];
        int h = c >> 6, dk = c & 63;
        #pragma unroll
        for (int m = 0; m < 4; ++m) {
            #pragma unroll
            for (int i = 0; i < 4; ++i) {
                int r = wr * 64 + m * 16 + rbase + i;
                if (r < rows) {
                    int tok = stok[r];
                    int b = tok >> 9, s = tok & 511;
                    float val = acc[m][n][i] + bv_;
                    if (proj == 0)
                        qb[((size_t)((b * NH + h) * NS + s) << 6) + dk] = f2bf(val * SCALE_LOG2E);
                    else if (proj == 1)
                        kbf[((size_t)((b * NH + h) * NS + s) << 6) + dk] = f2bf(val);
                    else
                        vtb[(size_t)((b * NH + h) * NDK + dk) * NS + s] = f2bf(val);
                }
            }
        }
    }
}

// ---------------- MFMA flash attention: 4 waves x 16 q-rows, K-tiles of 64 ----------------
__global__ __launch_bounds__(256) void attn_mfma(
    const u16* __restrict__ qb, const u16* __restrict__ kbf, const u16* __restrict__ vtb,
    const u64* __restrict__ maskb, u16* __restrict__ attb)
{
    int bh = blockIdx.y;
    int b = bh >> 3, h = bh & 7;
    int q0 = blockIdx.x * 64;
    int tid = threadIdx.x, lane = tid & 63, w = tid >> 6;
    int ln15 = lane & 15, g = lane >> 4;

    __shared__ __align__(16) u16 sK[64 * 64];    // [key][dk], XOR-swizzled
    __shared__ __align__(16) u16 sVt[64 * 64];   // [dk][key], XOR-swizzled
    __shared__ __align__(16) u16 sP[4 * 16 * 72];// per-wave [q][key] stride 72

    // Q A-fragments (row = ln15, k-slice = g*8), pre-scaled by SCALE*log2e
    const u16* Qg = qb + ((size_t)(bh * NS + q0 + w * 16 + ln15) << 6);
    short8 aq0 = *reinterpret_cast<const short8*>(Qg + g * 8);
    short8 aq1 = *reinterpret_cast<const short8*>(Qg + 32 + g * 8);

    const u16* Kg = kbf + ((size_t)bh << 15);    // [s][dk]
    const u16* Vtg = vtb + ((size_t)bh << 15);   // [dk][s]
    int srow = tid >> 3, schunk = tid & 7;       // staging: 32 rows x 8 chunks per pass

    const u64* Mrow = maskb + (size_t)((b << 9) + q0 + w * 16 + g * 4) * 8;

    f32x4 acc_o[4] = {};
    float mrun[4], lrun[4];
    #pragma unroll
    for (int i = 0; i < 4; ++i) { mrun[i] = -3.0e38f; lrun[i] = 0.f; }

    // prefetch tile 0
    short8 kpre0 = *reinterpret_cast<const short8*>(Kg + ((size_t)srow << 6) + schunk * 8);
    short8 kpre1 = *reinterpret_cast<const short8*>(Kg + ((size_t)(srow + 32) << 6) + schunk * 8);
    short8 vpre0 = *reinterpret_cast<const short8*>(Vtg + (size_t)srow * NS + schunk * 8);
    short8 vpre1 = *reinterpret_cast<const short8*>(Vtg + (size_t)(srow + 32) * NS + schunk * 8);

    u16* sPw = sP + w * 16 * 72;

    for (int j = 0; j < 8; ++j) {
        __syncthreads();                          // prior readers of sK/sVt done
        {
            int r2 = srow + 32;
            *reinterpret_cast<short8*>((char*)sK  + srow * 128 + ((schunk * 16) ^ ((srow & 7) << 4))) = kpre0;
            *reinterpret_cast<short8*>((char*)sK  + r2   * 128 + ((schunk * 16) ^ ((r2   & 7) << 4))) = kpre1;
            *reinterpret_cast<short8*>((char*)sVt + srow * 128 + ((schunk * 16) ^ ((srow & 7) << 4))) = vpre0;
            *reinterpret_cast<short8*>((char*)sVt + r2   * 128 + ((schunk * 16) ^ ((r2   & 7) << 4))) = vpre1;
        }
        if (j < 7) {                              // prefetch next tile (in flight across barrier)
            int j1 = j + 1;
            kpre0 = *reinterpret_cast<const short8*>(Kg + ((size_t)(j1 * 64 + srow) << 6) + schunk * 8);
            kpre1 = *reinterpret_cast<const short8*>(Kg + ((size_t)(j1 * 64 + srow + 32) << 6) + schunk * 8);
            vpre0 = *reinterpret_cast<const short8*>(Vtg + (size_t)srow * NS + j1 * 64 + schunk * 8);
            vpre1 = *reinterpret_cast<const short8*>(Vtg + (size_t)(srow + 32) * NS + j1 * 64 + schunk * 8);
        }
        __syncthreads();

        // QK^T: S[q=(g*4+i)][key=n*16+ln15], 8 MFMA
        f32x4 accs[4] = {};
        #pragma unroll
        for (int ks = 0; ks < 2; ++ks) {
            short8 a = ks ? aq1 : aq0;
            #pragma unroll
            for (int n = 0; n < 4; ++n) {
                int row = n * 16 + ln15;
                short8 bk = *reinterpret_cast<const short8*>(
                    (char*)sK + row * 128 + (((ks * 64) + g * 16) ^ ((row & 7) << 4)));
                accs[n] = __builtin_amdgcn_mfma_f32_16x16x32_bf16(a, bk, accs[n], 0, 0, 0);
            }
        }

        // online softmax per q-row i
        #pragma unroll
        for (int i = 0; i < 4; ++i) {
            u64 mw = Mrow[(size_t)i * 8 + j];
            float sv[4];
            #pragma unroll
            for (int n = 0; n < 4; ++n)
                sv[n] = ((mw >> (n * 16 + ln15)) & 1ull) ? accs[n][i] : -1.0e9f;
            float mx = fmaxf(fmaxf(sv[0], sv[1]), fmaxf(sv[2], sv[3]));
            #pragma unroll
            for (int d = 1; d < 16; d <<= 1) mx = fmaxf(mx, __shfl_xor(mx, d));
            float nm = fmaxf(mrun[i], mx);
            float sc = exp2f(mrun[i] - nm);
            float ps = 0.f;
            #pragma unroll
            for (int n = 0; n < 4; ++n) {
                float p = exp2f(sv[n] - nm);
                ps += p;
                sPw[(g * 4 + i) * 72 + n * 16 + ln15] = f2bf(p);
            }
            mrun[i] = nm;
            lrun[i] = lrun[i] * sc + ps;
            #pragma unroll
            for (int n2 = 0; n2 < 4; ++n2) acc_o[n2][i] *= sc;
        }

        // PV: O[q][dk=n2*16+ln15] += P @ V^T, 8 MFMA (sP same-wave: compiler orders lgkm)
        #pragma unroll
        for (int ks = 0; ks < 2; ++ks) {
            short8 ap = *reinterpret_cast<const short8*>(
                (char*)sPw + ((ln15 * 72 + ks * 32 + g * 8) << 1));
            #pragma unroll
            for (int n2 = 0; n2 < 4; ++n2) {
                int row = n2 * 16 + ln15;
                short8 bv = *reinterpret_cast<const short8*>(
                    (char*)sVt + row * 128 + (((ks * 64) + g * 16) ^ ((row & 7) << 4)));
                acc_o[n2] = __builtin_amdgcn_mfma_f32_16x16x32_bf16(ap, bv, acc_o[n2], 0, 0, 0);
            }
        }
    }

    // epilogue: reduce l across the 16-lane group, normalize, store bf16
    float linv[4];
    #pragma unroll
    for (int i = 0; i < 4; ++i) {
        float l = lrun[i];
        #pragma unroll
        for (int d = 1; d < 16; d <<= 1) l += __shfl_xor(l, d);
        linv[i] = 1.f / l;
    }
    #pragma unroll
    for (int n2 = 0; n2 < 4; ++n2) {
        #pragma unroll
        for (int i = 0; i < 4; ++i) {
            int q = q0 + w * 16 + g * 4 + i;
            attb[((size_t)((b << 9) + q) << 9) + (h << 6) + n2 * 16 + ln15] =
                f2bf(acc_o[n2][i] * linv[i]);
        }
    }
}

// ---------------- grouped out-proj GEMM + bias + residual ----------------
__global__ __launch_bounds__(256) void out_gemm(
    const u16* __restrict__ attb, const u16* __restrict__ Wat, const float* __restrict__ ba,
    const int* __restrict__ perm, const int* __restrict__ typeoff,
    const int* __restrict__ tile_type, const int* __restrict__ tile_row0, const int* __restrict__ ntiles,
    const float* __restrict__ x, float* __restrict__ hbuf)
{
    if (blockIdx.x >= *ntiles) return;
    int t = tile_type[blockIdx.x];
    int row0 = tile_row0[blockIdx.x];
    int rows = typeoff[t + 1] - row0; if (rows > BM) rows = BM;
    int col0 = blockIdx.y * BN;
    const u16* W = Wat + ((size_t)t << 18);
    const float* bias = ba + (t << 9);

    __shared__ __align__(16) u16 As[BM][BKK];
    __shared__ __align__(16) u16 Bs[BN][BKK];
    __shared__ int stok[BM];

    int tid = threadIdx.x;
    if (tid < BM) stok[tid] = perm[row0 + (tid < rows ? tid : 0)];
    __syncthreads();

    int lane = tid & 63, wave = tid >> 6;
    int wr = wave >> 1, wc = wave & 1;
    int fr = lane & 15, fk = (lane >> 4) << 3;

    f32x4 acc[4][4] = {};

    for (int k0 = 0; k0 < ND; k0 += BKK) {
        #pragma unroll
        for (int c = 0; c < 4; ++c) {
            int idx = c * 256 + tid;
            int r = idx >> 3, cc = (idx & 7) << 3;
            *reinterpret_cast<short8*>(&As[r][cc]) =
                *reinterpret_cast<const short8*>(attb + ((size_t)stok[r] << 9) + k0 + cc);
            *reinterpret_cast<short8*>(&Bs[r][cc]) =
                *reinterpret_cast<const short8*>(W + ((size_t)(col0 + r) << 9) + k0 + cc);
        }
        __syncthreads();
        #pragma unroll
        for (int ks = 0; ks < 2; ++ks) {
            short8 af[4], bfr[4];
            #pragma unroll
            for (int m = 0; m < 4; ++m)
                af[m] = *reinterpret_cast<const short8*>(&As[wr * 64 + m * 16 + fr][ks * 32 + fk]);
            #pragma unroll
            for (int n = 0; n < 4; ++n)
                bfr[n] = *reinterpret_cast<const short8*>(&Bs[wc * 64 + n * 16 + fr][ks * 32 + fk]);
            #pragma unroll
            for (int m = 0; m < 4; ++m)
                #pragma unroll
                for (int n = 0; n < 4; ++n)
                    acc[m][n] = __builtin_amdgcn_mfma_f32_16x16x32_bf16(af[m], bfr[n], acc[m][n], 0, 0, 0);
        }
        __syncthreads();
    }

    int rbase = (lane >> 4) << 2;
    #pragma unroll
    for (int n = 0; n < 4; ++n) {
        int c = col0 + wc * 64 + n * 16 + fr;
        float bv_ = bias[c];
        #pragma unroll
        for (int m = 0; m < 4; ++m) {
            #pragma unroll
            for (int i = 0; i < 4; ++i) {
                int r = wr * 64 + m * 16 + rbase + i;
                if (r < rows) {
                    int tok = stok[r];
                    size_t off = (size_t)tok * ND + c;
                    hbuf[off] = acc[m][n][i] + bv_ + x[off];
                }
            }
        }
    }
}

// ---------------- per-type LayerNorm ----------------
__global__ __launch_bounds__(256) void lnorm(
    const float* __restrict__ hbuf, const int* __restrict__ xty,
    const float* __restrict__ gamma, const float* __restrict__ beta, float* __restrict__ out)
{
    int row = blockIdx.x * 4 + (threadIdx.x >> 6);
    int lane = threadIdx.x & 63;
    const float4* h4 = reinterpret_cast<const float4*>(hbuf + (size_t)row * ND);
    float4 a = h4[lane * 2], b = h4[lane * 2 + 1];
    float sum = a.x + a.y + a.z + a.w + b.x + b.y + b.z + b.w;
    float sq = a.x * a.x + a.y * a.y + a.z * a.z + a.w * a.w
             + b.x * b.x + b.y * b.y + b.z * b.z + b.w * b.w;
    #pragma unroll
    for (int off = 32; off; off >>= 1) { sum += __shfl_xor(sum, off); sq += __shfl_xor(sq, off); }
    float mu = sum * (1.f / ND);
    float var = sq * (1.f / ND) - mu * mu;
    float is = rsqrtf(var + 1e-5f);
    int t = xty[row];
    const float4* g4 = reinterpret_cast<const float4*>(gamma + ((size_t)t << 9));
    const float4* be4 = reinterpret_cast<const float4*>(beta + ((size_t)t << 9));
    float4 g0 = g4[lane * 2], g1 = g4[lane * 2 + 1];
    float4 b0 = be4[lane * 2], b1 = be4[lane * 2 + 1];
    float4 o0, o1;
    o0.x = (a.x - mu) * is * g0.x + b0.x;
    o0.y = (a.y - mu) * is * g0.y + b0.y;
    o0.z = (a.z - mu) * is * g0.z + b0.z;
    o0.w = (a.w - mu) * is * g0.w + b0.w;
    o1.x = (b.x - mu) * is * g1.x + b1.x;
    o1.y = (b.y - mu) * is * g1.y + b1.y;
    o1.z = (b.z - mu) * is * g1.z + b1.z;
    o1.w = (b.w - mu) * is * g1.w + b1.w;
    float4* out4 = reinterpret_cast<float4*>(out + (size_t)row * ND);
    out4[lane * 2] = o0; out4[lane * 2 + 1] = o1;
}

extern "C" void kernel_launch(void* const* d_in, const int* in_sizes, int n_in,
                              void* d_out, int out_size, void* d_ws, size_t ws_size,
                              hipStream_t stream)
{
    const float* x     = (const float*)d_in[0];
    const int*   xty   = (const int*)d_in[1];
    const int*   mask  = (const int*)d_in[2];
    const float* Wq    = (const float*)d_in[3];
    const float* bq    = (const float*)d_in[4];
    const float* Wk    = (const float*)d_in[5];
    const float* bk    = (const float*)d_in[6];
    const float* Wv    = (const float*)d_in[7];
    const float* bv    = (const float*)d_in[8];
    const float* Wa    = (const float*)d_in[9];
    const float* ba    = (const float*)d_in[10];
    const float* gamma = (const float*)d_in[11];
    const float* beta  = (const float*)d_in[12];
    float* out = (float*)d_out;

    char* ws = (char*)d_ws;
    u16*   xb      = (u16*)(ws + 0);             //  8,388,608
    u16*   Wqt     = (u16*)(ws + 8388608);       //  4,194,304 each
    u16*   Wkt     = (u16*)(ws + 12582912);
    u16*   Wvt     = (u16*)(ws + 16777216);
    u16*   Wat     = (u16*)(ws + 20971520);
    u16*   qb      = (u16*)(ws + 25165824);      //  8,388,608 (bf16, pre-scaled)
    u16*   kbf     = (u16*)(ws + 33554432);      //  8,388,608
    u16*   vtb     = (u16*)(ws + 41943040);      //  8,388,608 (V^T: [bh][dk][s])
    u16*   attb    = (u16*)(ws + 50331648);      //  8,388,608
    float* hbuf    = (float*)(ws + 58720256);    // 16,777,216
    u64*   maskb   = (u64*)(ws + 75497472);      //    524,288
    int*   perm    = (int*)(ws + 76021760);      //     32,768
    int*   typeoff = (int*)(ws + 76054528);
    int*   ttile   = (int*)(ws + 76054592);
    int*   trow    = (int*)(ws + 76054912);
    int*   ntiles  = (int*)(ws + 76055232);

    bucketize<<<dim3(1), dim3(256), 0, stream>>>(xty, perm, typeoff, ttile, trow, ntiles);
    cvt_x<<<dim3(4096), dim3(256), 0, stream>>>(x, xb);
    cvt_w<<<dim3(8, 8, 32), dim3(256), 0, stream>>>(Wq, Wk, Wv, Wa, Wqt, Wkt, Wvt, Wat);
    pack_mask<<<dim3(16384), dim3(256), 0, stream>>>(mask, maskb);
    qkv_gemm<<<dim3(72, 12), dim3(256), 0, stream>>>(xb, Wqt, Wkt, Wvt, bq, bk, bv,
                                                     perm, typeoff, ttile, trow, ntiles, qb, kbf, vtb);
    attn_mfma<<<dim3(8, 128), dim3(256), 0, stream>>>(qb, kbf, vtb, maskb, attb);
    out_gemm<<<dim3(72, 4), dim3(256), 0, stream>>>(attb, Wat, ba,
                                                    perm, typeoff, ttile, trow, ntiles, x, hbuf);
    lnorm<<<dim3(2048), dim3(256), 0, stream>>>(hbuf, xty, gamma, beta, out);
}

// Round 3
// 279.335 us; speedup vs baseline: 3.4594x; 1.0713x over previous
//
#include <hip/hip_runtime.h>
#include <hip/hip_bf16.h>

typedef __attribute__((ext_vector_type(8))) short short8;
typedef __attribute__((ext_vector_type(4))) float f32x4;
typedef __attribute__((ext_vector_type(4))) unsigned short u16x4;
typedef unsigned short u16;
typedef unsigned long long u64;

#define NB 16
#define NS 512
#define ND 512
#define NH 8
#define NT 8
#define NDK 64
#define NN (NB*NS)
#define SCALE_LOG2E 0.18033688011112042f   // (1/sqrt(64)) * log2(e)
#define BM 128
#define BN 128
#define BKK 64

__device__ __forceinline__ u16 f2bf(float f) {
    __hip_bfloat16 h = __float2bfloat16(f);
    return *reinterpret_cast<u16*>(&h);
}

typedef const __attribute__((address_space(1))) void* gas_t;
typedef __attribute__((address_space(3))) void* las_t;

__device__ __forceinline__ void gload16(const void* gsrc, void* ldst) {
    __builtin_amdgcn_global_load_lds((gas_t)gsrc, (las_t)ldst, 16, 0, 0);
}

// ---------------- bucketize tokens by type ----------------
__global__ __launch_bounds__(256) void bucketize(
    const int* __restrict__ xty, int* __restrict__ perm, int* __restrict__ typeoff,
    int* __restrict__ tile_type, int* __restrict__ tile_row0, int* __restrict__ ntiles)
{
    __shared__ int cnt[NT], off[NT + 1], cur[NT];
    int tid = threadIdx.x;
    if (tid < NT) cnt[tid] = 0;
    __syncthreads();
    for (int n = tid; n < NN; n += 256) atomicAdd(&cnt[xty[n]], 1);
    __syncthreads();
    if (tid == 0) {
        int acc = 0, nt = 0;
        for (int t = 0; t < NT; ++t) {
            off[t] = acc;
            for (int r = 0; r < cnt[t]; r += BM) { tile_type[nt] = t; tile_row0[nt] = acc + r; ++nt; }
            acc += cnt[t];
        }
        off[NT] = acc;
        *ntiles = nt;
        for (int t = 0; t <= NT; ++t) typeoff[t] = off[t];
    }
    __syncthreads();
    if (tid < NT) cur[tid] = off[tid];
    __syncthreads();
    for (int n = tid; n < NN; n += 256) {
        int t = xty[n];
        int p = atomicAdd(&cur[t], 1);
        perm[p] = n;
    }
}

// ---------------- x f32 -> bf16 ----------------
__global__ __launch_bounds__(256) void cvt_x(const float* __restrict__ x, u16* __restrict__ xb)
{
    int i = blockIdx.x * 256 + threadIdx.x;
    float4 v = reinterpret_cast<const float4*>(x)[i];
    u16x4 o;
    o.x = f2bf(v.x); o.y = f2bf(v.y); o.z = f2bf(v.z); o.w = f2bf(v.w);
    reinterpret_cast<u16x4*>(xb)[i] = o;
}

// ---------------- W [t][d][h] f32 -> Wt [t][h][d] bf16 (transpose+convert) ----------------
__global__ __launch_bounds__(256) void cvt_w(
    const float* __restrict__ Wq, const float* __restrict__ Wk,
    const float* __restrict__ Wv, const float* __restrict__ Wa,
    u16* __restrict__ Wqt, u16* __restrict__ Wkt, u16* __restrict__ Wvt, u16* __restrict__ Wat)
{
    int arr = blockIdx.z >> 3, t = blockIdx.z & 7;
    const float* W = (arr == 0 ? Wq : arr == 1 ? Wk : arr == 2 ? Wv : Wa) + ((size_t)t << 18);
    u16* O = (arr == 0 ? Wqt : arr == 1 ? Wkt : arr == 2 ? Wvt : Wat) + ((size_t)t << 18);
    int d0 = blockIdx.x * 64, h0 = blockIdx.y * 64;
    __shared__ __align__(16) float tile[64][68];
    int tx = threadIdx.x & 15, ty = threadIdx.x >> 4;
    #pragma unroll
    for (int i = 0; i < 4; ++i) {
        int r = ty + i * 16;
        float4 v = *reinterpret_cast<const float4*>(&W[(size_t)(d0 + r) * ND + h0 + tx * 4]);
        *reinterpret_cast<float4*>(&tile[r][tx * 4]) = v;
    }
    __syncthreads();
    #pragma unroll
    for (int i = 0; i < 4; ++i) {
        int r = ty + i * 16;
        u16x4 o;
        o.x = f2bf(tile[tx * 4 + 0][r]);
        o.y = f2bf(tile[tx * 4 + 1][r]);
        o.z = f2bf(tile[tx * 4 + 2][r]);
        o.w = f2bf(tile[tx * 4 + 3][r]);
        *reinterpret_cast<u16x4*>(&O[(size_t)(h0 + r) * ND + d0 + tx * 4]) = o;
    }
}

// ---------------- bitpack mask: 64 keys -> one u64 ----------------
__global__ __launch_bounds__(256) void pack_mask(const int* __restrict__ mask, u64* __restrict__ maskb)
{
    int i = blockIdx.x * 256 + threadIdx.x;
    int v = mask[i];
    u64 bal = __ballot(v != 0);
    if ((threadIdx.x & 63) == 0) maskb[i >> 6] = bal;
}

// ---------------- grouped GEMM: q/k/v = xb @ W[t]^T + b ; all outputs [bh][s][dk] ----------------
// LDS linear + pre-swizzled global source chunk; fragment reads XOR-swizzled (rule #21).
__global__ __launch_bounds__(256) void qkv_gemm(
    const u16* __restrict__ xb,
    const u16* __restrict__ Wqt, const u16* __restrict__ Wkt, const u16* __restrict__ Wvt,
    const float* __restrict__ bq, const float* __restrict__ bk, const float* __restrict__ bv,
    const int* __restrict__ perm, const int* __restrict__ typeoff,
    const int* __restrict__ tile_type, const int* __restrict__ tile_row0, const int* __restrict__ ntiles,
    u16* __restrict__ qb, u16* __restrict__ kbf, u16* __restrict__ vb)
{
    if (blockIdx.x >= *ntiles) return;
    int t = tile_type[blockIdx.x];
    int row0 = tile_row0[blockIdx.x];
    int rows = typeoff[t + 1] - row0; if (rows > BM) rows = BM;
    int proj = blockIdx.y >> 2;
    int col0 = (blockIdx.y & 3) * BN;
    const u16* W = (proj == 0 ? Wqt : proj == 1 ? Wkt : Wvt) + ((size_t)t << 18);
    const float* bias = (proj == 0 ? bq : proj == 1 ? bk : bv) + (t << 9);
    u16* outp = proj == 0 ? qb : proj == 1 ? kbf : vb;
    float qscale = proj == 0 ? SCALE_LOG2E : 1.f;

    __shared__ __align__(16) u16 As[BM][BKK];
    __shared__ __align__(16) u16 Bs[BN][BKK];
    __shared__ int stok[BM];

    int tid = threadIdx.x;
    if (tid < BM) stok[tid] = perm[row0 + (tid < rows ? tid : 0)];
    __syncthreads();

    int lane = tid & 63, w = tid >> 6;
    int wr = w >> 1, wc = w & 1;
    int fr = lane & 15, g = lane >> 4;

    // staging geometry: wave w stages rows [w*32, w*32+32), instruction k covers 8 rows
    int lrow = lane >> 3;                       // 0..7 within the 8-row group
    int schunk = (lane & 7) ^ lrow;             // pre-swizzled source chunk (16B units)
    int tokA[4];
    #pragma unroll
    for (int k = 0; k < 4; ++k) tokA[k] = stok[w * 32 + k * 8 + lrow];

    f32x4 acc[4][4] = {};

    for (int k0 = 0; k0 < ND; k0 += BKK) {
        __syncthreads();                        // previous iteration's LDS reads complete
        #pragma unroll
        for (int k = 0; k < 4; ++k) {
            gload16(xb + (((size_t)tokA[k]) << 9) + k0 + schunk * 8, &As[w * 32 + k * 8][0]);
            gload16(W + (((size_t)(col0 + w * 32 + k * 8 + lrow)) << 9) + k0 + schunk * 8,
                    &Bs[w * 32 + k * 8][0]);
        }
        __syncthreads();                        // drains vmcnt -> LDS tiles ready

        const char* Ab = (const char*)As;
        const char* Bb = (const char*)Bs;
        #pragma unroll
        for (int ks = 0; ks < 2; ++ks) {
            short8 af[4], bfr[4];
            #pragma unroll
            for (int m = 0; m < 4; ++m) {
                int r = wr * 64 + m * 16 + fr;
                af[m] = *reinterpret_cast<const short8*>(Ab + r * 128 + (((ks * 4 + g) ^ (r & 7)) << 4));
            }
            #pragma unroll
            for (int n = 0; n < 4; ++n) {
                int r = wc * 64 + n * 16 + fr;
                bfr[n] = *reinterpret_cast<const short8*>(Bb + r * 128 + (((ks * 4 + g) ^ (r & 7)) << 4));
            }
            #pragma unroll
            for (int m = 0; m < 4; ++m)
                #pragma unroll
                for (int n = 0; n < 4; ++n)
                    acc[m][n] = __builtin_amdgcn_mfma_f32_16x16x32_bf16(af[m], bfr[n], acc[m][n], 0, 0, 0);
        }
    }

    int rbase = g << 2;
    #pragma unroll
    for (int n = 0; n < 4; ++n) {
        int c = col0 + wc * 64 + n * 16 + fr;     // [0,512)
        float bv_ = bias[c];
        int h = c >> 6, dk = c & 63;
        #pragma unroll
        for (int m = 0; m < 4; ++m) {
            #pragma unroll
            for (int i = 0; i < 4; ++i) {
                int r = wr * 64 + m * 16 + rbase + i;
                if (r < rows) {
                    int tok = stok[r];
                    int b = tok >> 9, s = tok & 511;
                    outp[((size_t)((b * NH + h) * NS + s) << 6) + dk] =
                        f2bf((acc[m][n][i] + bv_) * qscale);
                }
            }
        }
    }
}

// ---------------- V transpose: vb [bh][s][dk] -> vtb [bh][dk][s], coalesced both sides ----------------
__global__ __launch_bounds__(256) void transp_v(const u16* __restrict__ vb, u16* __restrict__ vtb)
{
    int bh = blockIdx.y, s0 = blockIdx.x * 64;
    __shared__ __align__(16) u16 t[64][72];
    int tid = threadIdx.x;
    const u16* src = vb + ((size_t)bh << 15) + ((size_t)s0 << 6);
    #pragma unroll
    for (int it = 0; it < 2; ++it) {
        int idx = it * 256 + tid;
        int s = idx & 63, c = idx >> 6;           // per-wave fixed chunk; lanes span 64 s-rows
        short8 v = *reinterpret_cast<const short8*>(src + ((size_t)s << 6) + c * 8);
        #pragma unroll
        for (int j = 0; j < 8; ++j) t[c * 8 + j][s] = ((const u16*)&v)[j];  // same dk row/instr: 2-way max
    }
    __syncthreads();
    u16* dst = vtb + ((size_t)bh << 15) + s0;
    #pragma unroll
    for (int it = 0; it < 2; ++it) {
        int idx = it * 256 + tid;
        int dk = idx >> 3, c = idx & 7;
        short8 v = *reinterpret_cast<const short8*>(&t[dk][c * 8]);
        *reinterpret_cast<short8*>(dst + (size_t)dk * NS + c * 8) = v;
    }
}

// ---------------- MFMA flash attention: 4 waves x 16 q-rows, K-tiles of 64 ----------------
__global__ __launch_bounds__(256) void attn_mfma(
    const u16* __restrict__ qb, const u16* __restrict__ kbf, const u16* __restrict__ vtb,
    const u64* __restrict__ maskb, u16* __restrict__ attb)
{
    int bh = blockIdx.y;
    int b = bh >> 3, h = bh & 7;
    int q0 = blockIdx.x * 64;
    int tid = threadIdx.x, lane = tid & 63, w = tid >> 6;
    int ln15 = lane & 15, g = lane >> 4;

    __shared__ __align__(16) u16 sK[64 * 64];    // [key][dk], XOR-swizzled
    __shared__ __align__(16) u16 sVt[64 * 64];   // [dk][key], XOR-swizzled
    __shared__ __align__(16) u16 sP[4 * 16 * 72];// per-wave [q][key] stride 72

    const u16* Qg = qb + ((size_t)(bh * NS + q0 + w * 16 + ln15) << 6);
    short8 aq0 = *reinterpret_cast<const short8*>(Qg + g * 8);
    short8 aq1 = *reinterpret_cast<const short8*>(Qg + 32 + g * 8);

    const u16* Kg = kbf + ((size_t)bh << 15);    // [s][dk]
    const u16* Vtg = vtb + ((size_t)bh << 15);   // [dk][s]
    int srow = tid >> 3, schunk = tid & 7;

    const u64* Mrow = maskb + (size_t)((b << 9) + q0 + w * 16 + g * 4) * 8;

    f32x4 acc_o[4] = {};
    float mrun[4], lrun[4];
    #pragma unroll
    for (int i = 0; i < 4; ++i) { mrun[i] = -3.0e38f; lrun[i] = 0.f; }

    short8 kpre0 = *reinterpret_cast<const short8*>(Kg + ((size_t)srow << 6) + schunk * 8);
    short8 kpre1 = *reinterpret_cast<const short8*>(Kg + ((size_t)(srow + 32) << 6) + schunk * 8);
    short8 vpre0 = *reinterpret_cast<const short8*>(Vtg + (size_t)srow * NS + schunk * 8);
    short8 vpre1 = *reinterpret_cast<const short8*>(Vtg + (size_t)(srow + 32) * NS + schunk * 8);

    u16* sPw = sP + w * 16 * 72;

    for (int j = 0; j < 8; ++j) {
        __syncthreads();
        {
            int r2 = srow + 32;
            *reinterpret_cast<short8*>((char*)sK  + srow * 128 + ((schunk * 16) ^ ((srow & 7) << 4))) = kpre0;
            *reinterpret_cast<short8*>((char*)sK  + r2   * 128 + ((schunk * 16) ^ ((r2   & 7) << 4))) = kpre1;
            *reinterpret_cast<short8*>((char*)sVt + srow * 128 + ((schunk * 16) ^ ((srow & 7) << 4))) = vpre0;
            *reinterpret_cast<short8*>((char*)sVt + r2   * 128 + ((schunk * 16) ^ ((r2   & 7) << 4))) = vpre1;
        }
        if (j < 7) {
            int j1 = j + 1;
            kpre0 = *reinterpret_cast<const short8*>(Kg + ((size_t)(j1 * 64 + srow) << 6) + schunk * 8);
            kpre1 = *reinterpret_cast<const short8*>(Kg + ((size_t)(j1 * 64 + srow + 32) << 6) + schunk * 8);
            vpre0 = *reinterpret_cast<const short8*>(Vtg + (size_t)srow * NS + j1 * 64 + schunk * 8);
            vpre1 = *reinterpret_cast<const short8*>(Vtg + (size_t)(srow + 32) * NS + j1 * 64 + schunk * 8);
        }
        __syncthreads();

        f32x4 accs[4] = {};
        #pragma unroll
        for (int ks = 0; ks < 2; ++ks) {
            short8 a = ks ? aq1 : aq0;
            #pragma unroll
            for (int n = 0; n < 4; ++n) {
                int row = n * 16 + ln15;
                short8 bk = *reinterpret_cast<const short8*>(
                    (char*)sK + row * 128 + (((ks * 64) + g * 16) ^ ((row & 7) << 4)));
                accs[n] = __builtin_amdgcn_mfma_f32_16x16x32_bf16(a, bk, accs[n], 0, 0, 0);
            }
        }

        #pragma unroll
        for (int i = 0; i < 4; ++i) {
            u64 mw = Mrow[(size_t)i * 8 + j];
            float sv[4];
            #pragma unroll
            for (int n = 0; n < 4; ++n)
                sv[n] = ((mw >> (n * 16 + ln15)) & 1ull) ? accs[n][i] : -1.0e9f;
            float mx = fmaxf(fmaxf(sv[0], sv[1]), fmaxf(sv[2], sv[3]));
            #pragma unroll
            for (int d = 1; d < 16; d <<= 1) mx = fmaxf(mx, __shfl_xor(mx, d));
            float nm = fmaxf(mrun[i], mx);
            float sc = exp2f(mrun[i] - nm);
            float ps = 0.f;
            #pragma unroll
            for (int n = 0; n < 4; ++n) {
                float p = exp2f(sv[n] - nm);
                ps += p;
                sPw[(g * 4 + i) * 72 + n * 16 + ln15] = f2bf(p);
            }
            mrun[i] = nm;
            lrun[i] = lrun[i] * sc + ps;
            #pragma unroll
            for (int n2 = 0; n2 < 4; ++n2) acc_o[n2][i] *= sc;
        }

        #pragma unroll
        for (int ks = 0; ks < 2; ++ks) {
            short8 ap = *reinterpret_cast<const short8*>(
                (char*)sPw + ((ln15 * 72 + ks * 32 + g * 8) << 1));
            #pragma unroll
            for (int n2 = 0; n2 < 4; ++n2) {
                int row = n2 * 16 + ln15;
                short8 bv = *reinterpret_cast<const short8*>(
                    (char*)sVt + row * 128 + (((ks * 64) + g * 16) ^ ((row & 7) << 4)));
                acc_o[n2] = __builtin_amdgcn_mfma_f32_16x16x32_bf16(ap, bv, acc_o[n2], 0, 0, 0);
            }
        }
    }

    float linv[4];
    #pragma unroll
    for (int i = 0; i < 4; ++i) {
        float l = lrun[i];
        #pragma unroll
        for (int d = 1; d < 16; d <<= 1) l += __shfl_xor(l, d);
        linv[i] = 1.f / l;
    }
    #pragma unroll
    for (int n2 = 0; n2 < 4; ++n2) {
        #pragma unroll
        for (int i = 0; i < 4; ++i) {
            int q = q0 + w * 16 + g * 4 + i;
            attb[((size_t)((b << 9) + q) << 9) + (h << 6) + n2 * 16 + ln15] =
                f2bf(acc_o[n2][i] * linv[i]);
        }
    }
}

// ---------------- grouped out-proj GEMM + bias + residual ----------------
__global__ __launch_bounds__(256) void out_gemm(
    const u16* __restrict__ attb, const u16* __restrict__ Wat, const float* __restrict__ ba,
    const int* __restrict__ perm, const int* __restrict__ typeoff,
    const int* __restrict__ tile_type, const int* __restrict__ tile_row0, const int* __restrict__ ntiles,
    const float* __restrict__ x, float* __restrict__ hbuf)
{
    if (blockIdx.x >= *ntiles) return;
    int t = tile_type[blockIdx.x];
    int row0 = tile_row0[blockIdx.x];
    int rows = typeoff[t + 1] - row0; if (rows > BM) rows = BM;
    int col0 = blockIdx.y * BN;
    const u16* W = Wat + ((size_t)t << 18);
    const float* bias = ba + (t << 9);

    __shared__ __align__(16) u16 As[BM][BKK];
    __shared__ __align__(16) u16 Bs[BN][BKK];
    __shared__ int stok[BM];

    int tid = threadIdx.x;
    if (tid < BM) stok[tid] = perm[row0 + (tid < rows ? tid : 0)];
    __syncthreads();

    int lane = tid & 63, w = tid >> 6;
    int wr = w >> 1, wc = w & 1;
    int fr = lane & 15, g = lane >> 4;

    int lrow = lane >> 3;
    int schunk = (lane & 7) ^ lrow;
    int tokA[4];
    #pragma unroll
    for (int k = 0; k < 4; ++k) tokA[k] = stok[w * 32 + k * 8 + lrow];

    f32x4 acc[4][4] = {};

    for (int k0 = 0; k0 < ND; k0 += BKK) {
        __syncthreads();
        #pragma unroll
        for (int k = 0; k < 4; ++k) {
            gload16(attb + (((size_t)tokA[k]) << 9) + k0 + schunk * 8, &As[w * 32 + k * 8][0]);
            gload16(W + (((size_t)(col0 + w * 32 + k * 8 + lrow)) << 9) + k0 + schunk * 8,
                    &Bs[w * 32 + k * 8][0]);
        }
        __syncthreads();

        const char* Ab = (const char*)As;
        const char* Bb = (const char*)Bs;
        #pragma unroll
        for (int ks = 0; ks < 2; ++ks) {
            short8 af[4], bfr[4];
            #pragma unroll
            for (int m = 0; m < 4; ++m) {
                int r = wr * 64 + m * 16 + fr;
                af[m] = *reinterpret_cast<const short8*>(Ab + r * 128 + (((ks * 4 + g) ^ (r & 7)) << 4));
            }
            #pragma unroll
            for (int n = 0; n < 4; ++n) {
                int r = wc * 64 + n * 16 + fr;
                bfr[n] = *reinterpret_cast<const short8*>(Bb + r * 128 + (((ks * 4 + g) ^ (r & 7)) << 4));
            }
            #pragma unroll
            for (int m = 0; m < 4; ++m)
                #pragma unroll
                for (int n = 0; n < 4; ++n)
                    acc[m][n] = __builtin_amdgcn_mfma_f32_16x16x32_bf16(af[m], bfr[n], acc[m][n], 0, 0, 0);
        }
    }

    int rbase = g << 2;
    #pragma unroll
    for (int n = 0; n < 4; ++n) {
        int c = col0 + wc * 64 + n * 16 + fr;
        float bv_ = bias[c];
        #pragma unroll
        for (int m = 0; m < 4; ++m) {
            #pragma unroll
            for (int i = 0; i < 4; ++i) {
                int r = wr * 64 + m * 16 + rbase + i;
                if (r < rows) {
                    int tok = stok[r];
                    size_t off = (size_t)tok * ND + c;
                    hbuf[off] = acc[m][n][i] + bv_ + x[off];
                }
            }
        }
    }
}

// ---------------- per-type LayerNorm ----------------
__global__ __launch_bounds__(256) void lnorm(
    const float* __restrict__ hbuf, const int* __restrict__ xty,
    const float* __restrict__ gamma, const float* __restrict__ beta, float* __restrict__ out)
{
    int row = blockIdx.x * 4 + (threadIdx.x >> 6);
    int lane = threadIdx.x & 63;
    const float4* h4 = reinterpret_cast<const float4*>(hbuf + (size_t)row * ND);
    float4 a = h4[lane * 2], b = h4[lane * 2 + 1];
    float sum = a.x + a.y + a.z + a.w + b.x + b.y + b.z + b.w;
    float sq = a.x * a.x + a.y * a.y + a.z * a.z + a.w * a.w
             + b.x * b.x + b.y * b.y + b.z * b.z + b.w * b.w;
    #pragma unroll
    for (int off = 32; off; off >>= 1) { sum += __shfl_xor(sum, off); sq += __shfl_xor(sq, off); }
    float mu = sum * (1.f / ND);
    float var = sq * (1.f / ND) - mu * mu;
    float is = rsqrtf(var + 1e-5f);
    int t = xty[row];
    const float4* g4 = reinterpret_cast<const float4*>(gamma + ((size_t)t << 9));
    const float4* be4 = reinterpret_cast<const float4*>(beta + ((size_t)t << 9));
    float4 g0 = g4[lane * 2], g1 = g4[lane * 2 + 1];
    float4 b0 = be4[lane * 2], b1 = be4[lane * 2 + 1];
    float4 o0, o1;
    o0.x = (a.x - mu) * is * g0.x + b0.x;
    o0.y = (a.y - mu) * is * g0.y + b0.y;
    o0.z = (a.z - mu) * is * g0.z + b0.z;
    o0.w = (a.w - mu) * is * g0.w + b0.w;
    o1.x = (b.x - mu) * is * g1.x + b1.x;
    o1.y = (b.y - mu) * is * g1.y + b1.y;
    o1.z = (b.z - mu) * is * g1.z + b1.z;
    o1.w = (b.w - mu) * is * g1.w + b1.w;
    float4* out4 = reinterpret_cast<float4*>(out + (size_t)row * ND);
    out4[lane * 2] = o0; out4[lane * 2 + 1] = o1;
}

extern "C" void kernel_launch(void* const* d_in, const int* in_sizes, int n_in,
                              void* d_out, int out_size, void* d_ws, size_t ws_size,
                              hipStream_t stream)
{
    const float* x     = (const float*)d_in[0];
    const int*   xty   = (const int*)d_in[1];
    const int*   mask  = (const int*)d_in[2];
    const float* Wq    = (const float*)d_in[3];
    const float* bq    = (const float*)d_in[4];
    const float* Wk    = (const float*)d_in[5];
    const float* bk    = (const float*)d_in[6];
    const float* Wv    = (const float*)d_in[7];
    const float* bv    = (const float*)d_in[8];
    const float* Wa    = (const float*)d_in[9];
    const float* ba    = (const float*)d_in[10];
    const float* gamma = (const float*)d_in[11];
    const float* beta  = (const float*)d_in[12];
    float* out = (float*)d_out;

    char* ws = (char*)d_ws;
    u16*   xb      = (u16*)(ws + 0);             //  8 MB
    u16*   Wqt     = (u16*)(ws + 8388608);       //  4 MB each
    u16*   Wkt     = (u16*)(ws + 12582912);
    u16*   Wvt     = (u16*)(ws + 16777216);
    u16*   Wat     = (u16*)(ws + 20971520);
    u16*   qb      = (u16*)(ws + 25165824);      //  8 MB (bf16, pre-scaled)
    u16*   kbf     = (u16*)(ws + 33554432);      //  8 MB
    u16*   vb      = (u16*)(ws + 41943040);      //  8 MB (V, [bh][s][dk])
    u16*   vtb     = (u16*)(ws + 50331648);      //  8 MB (V^T, [bh][dk][s])
    u16*   attb    = (u16*)(ws + 58720256);      //  8 MB
    float* hbuf    = (float*)(ws + 67108864);    // 16 MB
    u64*   maskb   = (u64*)(ws + 83886080);      // 512 KB
    int*   perm    = (int*)(ws + 84410368);      //  32 KB
    int*   typeoff = (int*)(ws + 84443136);
    int*   ttile   = (int*)(ws + 84443200);
    int*   trow    = (int*)(ws + 84443520);
    int*   ntiles  = (int*)(ws + 84443840);

    bucketize<<<dim3(1), dim3(256), 0, stream>>>(xty, perm, typeoff, ttile, trow, ntiles);
    cvt_x<<<dim3(4096), dim3(256), 0, stream>>>(x, xb);
    cvt_w<<<dim3(8, 8, 32), dim3(256), 0, stream>>>(Wq, Wk, Wv, Wa, Wqt, Wkt, Wvt, Wat);
    pack_mask<<<dim3(16384), dim3(256), 0, stream>>>(mask, maskb);
    qkv_gemm<<<dim3(72, 12), dim3(256), 0, stream>>>(xb, Wqt, Wkt, Wvt, bq, bk, bv,
                                                     perm, typeoff, ttile, trow, ntiles, qb, kbf, vb);
    transp_v<<<dim3(8, 128), dim3(256), 0, stream>>>(vb, vtb);
    attn_mfma<<<dim3(8, 128), dim3(256), 0, stream>>>(qb, kbf, vtb, maskb, attb);
    out_gemm<<<dim3(72, 4), dim3(256), 0, stream>>>(attb, Wat, ba,
                                                    perm, typeoff, ttile, trow, ntiles, x, hbuf);
    lnorm<<<dim3(2048), dim3(256), 0, stream>>>(hbuf, xty, gamma, beta, out);
}

// Round 4
// 270.864 us; speedup vs baseline: 3.5676x; 1.0313x over previous
//
#include <hip/hip_runtime.h>
#include <hip/hip_bf16.h>

typedef __attribute__((ext_vector_type(8))) short short8;
typedef __attribute__((ext_vector_type(4))) float f32x4;
typedef __attribute__((ext_vector_type(4))) unsigned short u16x4;
typedef unsigned short u16;
typedef unsigned int u32;
typedef unsigned long long u64;

#define NB 16
#define NS 512
#define ND 512
#define NH 8
#define NT 8
#define NDK 64
#define NN (NB*NS)
#define SCALE_LOG2E 0.18033688011112042f   // (1/sqrt(64)) * log2(e)
#define BM 128
#define BN 128
#define BKK 64

__device__ __forceinline__ u16 f2bf(float f) {
    __hip_bfloat16 h = __float2bfloat16(f);
    return *reinterpret_cast<u16*>(&h);
}
__device__ __forceinline__ u32 pk2(float lo, float hi) {
    return (u32)f2bf(lo) | ((u32)f2bf(hi) << 16);
}

typedef const __attribute__((address_space(1))) void* gas_t;
typedef __attribute__((address_space(3))) void* las_t;

__device__ __forceinline__ void gload16(const void* gsrc, void* ldst) {
    __builtin_amdgcn_global_load_lds((gas_t)gsrc, (las_t)ldst, 16, 0, 0);
}

// ---------------- bucketize tokens by type ----------------
__global__ __launch_bounds__(256) void bucketize(
    const int* __restrict__ xty, int* __restrict__ perm, int* __restrict__ typeoff,
    int* __restrict__ tile_type, int* __restrict__ tile_row0, int* __restrict__ ntiles)
{
    __shared__ int cnt[NT], off[NT + 1], cur[NT];
    int tid = threadIdx.x;
    if (tid < NT) cnt[tid] = 0;
    __syncthreads();
    for (int n = tid; n < NN; n += 256) atomicAdd(&cnt[xty[n]], 1);
    __syncthreads();
    if (tid == 0) {
        int acc = 0, nt = 0;
        for (int t = 0; t < NT; ++t) {
            off[t] = acc;
            for (int r = 0; r < cnt[t]; r += BM) { tile_type[nt] = t; tile_row0[nt] = acc + r; ++nt; }
            acc += cnt[t];
        }
        off[NT] = acc;
        *ntiles = nt;
        for (int t = 0; t <= NT; ++t) typeoff[t] = off[t];
    }
    __syncthreads();
    if (tid < NT) cur[tid] = off[tid];
    __syncthreads();
    for (int n = tid; n < NN; n += 256) {
        int t = xty[n];
        int p = atomicAdd(&cur[t], 1);
        perm[p] = n;
    }
}

// ---------------- x f32 -> bf16 ----------------
__global__ __launch_bounds__(256) void cvt_x(const float* __restrict__ x, u16* __restrict__ xb)
{
    int i = blockIdx.x * 256 + threadIdx.x;
    float4 v = reinterpret_cast<const float4*>(x)[i];
    u16x4 o;
    o.x = f2bf(v.x); o.y = f2bf(v.y); o.z = f2bf(v.z); o.w = f2bf(v.w);
    reinterpret_cast<u16x4*>(xb)[i] = o;
}

// ---------------- W [t][d][h] f32 -> Wt [t][h][d] bf16 (transpose+convert) ----------------
__global__ __launch_bounds__(256) void cvt_w(
    const float* __restrict__ Wq, const float* __restrict__ Wk,
    const float* __restrict__ Wv, const float* __restrict__ Wa,
    u16* __restrict__ Wqt, u16* __restrict__ Wkt, u16* __restrict__ Wvt, u16* __restrict__ Wat)
{
    int arr = blockIdx.z >> 3, t = blockIdx.z & 7;
    const float* W = (arr == 0 ? Wq : arr == 1 ? Wk : arr == 2 ? Wv : Wa) + ((size_t)t << 18);
    u16* O = (arr == 0 ? Wqt : arr == 1 ? Wkt : arr == 2 ? Wvt : Wat) + ((size_t)t << 18);
    int d0 = blockIdx.x * 64, h0 = blockIdx.y * 64;
    __shared__ __align__(16) float tile[64][68];
    int tx = threadIdx.x & 15, ty = threadIdx.x >> 4;
    #pragma unroll
    for (int i = 0; i < 4; ++i) {
        int r = ty + i * 16;
        float4 v = *reinterpret_cast<const float4*>(&W[(size_t)(d0 + r) * ND + h0 + tx * 4]);
        *reinterpret_cast<float4*>(&tile[r][tx * 4]) = v;
    }
    __syncthreads();
    #pragma unroll
    for (int i = 0; i < 4; ++i) {
        int r = ty + i * 16;
        u16x4 o;
        o.x = f2bf(tile[tx * 4 + 0][r]);
        o.y = f2bf(tile[tx * 4 + 1][r]);
        o.z = f2bf(tile[tx * 4 + 2][r]);
        o.w = f2bf(tile[tx * 4 + 3][r]);
        *reinterpret_cast<u16x4*>(&O[(size_t)(h0 + r) * ND + d0 + tx * 4]) = o;
    }
}

// ---------------- bitpack mask: 64 keys -> one u64 ----------------
__global__ __launch_bounds__(256) void pack_mask(const int* __restrict__ mask, u64* __restrict__ maskb)
{
    int i = blockIdx.x * 256 + threadIdx.x;
    int v = mask[i];
    u64 bal = __ballot(v != 0);
    if ((threadIdx.x & 63) == 0) maskb[i >> 6] = bal;
}

// ---------------- grouped GEMM: q/k/v = xb @ W[t]^T + b ; LDS dbuf + counted vmcnt ----------------
__global__ __launch_bounds__(256) void qkv_gemm(
    const u16* __restrict__ xb,
    const u16* __restrict__ Wqt, const u16* __restrict__ Wkt, const u16* __restrict__ Wvt,
    const float* __restrict__ bq, const float* __restrict__ bk, const float* __restrict__ bv,
    const int* __restrict__ perm, const int* __restrict__ typeoff,
    const int* __restrict__ tile_type, const int* __restrict__ tile_row0, const int* __restrict__ ntiles,
    u16* __restrict__ qb, u16* __restrict__ kbf, u16* __restrict__ vb)
{
    int work = (blockIdx.x & 7) * 108 + (blockIdx.x >> 3);  // XCD swizzle (864 = 8*108)
    int tile = work / 12, pc = work % 12;
    if (tile >= *ntiles) return;
    int t = tile_type[tile];
    int row0 = tile_row0[tile];
    int rows = typeoff[t + 1] - row0; if (rows > BM) rows = BM;
    int proj = pc >> 2;
    int col0 = (pc & 3) * BN;
    const u16* W = (proj == 0 ? Wqt : proj == 1 ? Wkt : Wvt) + ((size_t)t << 18);
    const float* bias = (proj == 0 ? bq : proj == 1 ? bk : bv) + (t << 9);
    u16* outp = proj == 0 ? qb : proj == 1 ? kbf : vb;
    float qscale = proj == 0 ? SCALE_LOG2E : 1.f;

    __shared__ __align__(16) u16 As[2][BM][BKK];
    __shared__ __align__(16) u16 Bs[2][BM][BKK];
    __shared__ int stok[BM];

    int tid = threadIdx.x;
    if (tid < BM) stok[tid] = perm[row0 + (tid < rows ? tid : 0)];
    __syncthreads();

    int lane = tid & 63, w = tid >> 6;
    int wr = w >> 1, wc = w & 1;
    int fr = lane & 15, g = lane >> 4;

    int lrow = lane >> 3;
    int schunk = (lane & 7) ^ lrow;             // pre-swizzled source chunk (16B units)
    int tokA[4];
    #pragma unroll
    for (int k = 0; k < 4; ++k) tokA[k] = stok[w * 32 + k * 8 + lrow];

    auto stage = [&](int buf, int k0) {
        #pragma unroll
        for (int k = 0; k < 4; ++k) {
            gload16(xb + (((size_t)tokA[k]) << 9) + k0 + schunk * 8, &As[buf][w * 32 + k * 8][0]);
            gload16(W + (((size_t)(col0 + w * 32 + k * 8 + lrow)) << 9) + k0 + schunk * 8,
                    &Bs[buf][w * 32 + k * 8][0]);
        }
    };

    f32x4 acc[4][4] = {};

    stage(0, 0);
    #pragma unroll
    for (int it = 0; it < 8; ++it) {
        int cur = it & 1;
        if (it < 7) {
            stage(cur ^ 1, (it + 1) * BKK);
            asm volatile("s_waitcnt vmcnt(8)" ::: "memory");   // cur's 8 loads done; next 8 in flight
        } else {
            asm volatile("s_waitcnt vmcnt(0)" ::: "memory");
        }
        __builtin_amdgcn_s_barrier();

        const char* Ab = (const char*)As[cur];
        const char* Bb = (const char*)Bs[cur];
        #pragma unroll
        for (int ks = 0; ks < 2; ++ks) {
            short8 af[4], bfr[4];
            #pragma unroll
            for (int m = 0; m < 4; ++m) {
                int r = wr * 64 + m * 16 + fr;
                af[m] = *reinterpret_cast<const short8*>(Ab + r * 128 + (((ks * 4 + g) ^ (r & 7)) << 4));
            }
            #pragma unroll
            for (int n = 0; n < 4; ++n) {
                int r = wc * 64 + n * 16 + fr;
                bfr[n] = *reinterpret_cast<const short8*>(Bb + r * 128 + (((ks * 4 + g) ^ (r & 7)) << 4));
            }
            #pragma unroll
            for (int m = 0; m < 4; ++m)
                #pragma unroll
                for (int n = 0; n < 4; ++n)
                    acc[m][n] = __builtin_amdgcn_mfma_f32_16x16x32_bf16(af[m], bfr[n], acc[m][n], 0, 0, 0);
        }
        asm volatile("s_waitcnt lgkmcnt(0)" ::: "memory");     // all LDS reads done before re-stage
        __builtin_amdgcn_s_barrier();
    }

    int rbase = g << 2;
    #pragma unroll
    for (int n = 0; n < 4; ++n) {
        int c = col0 + wc * 64 + n * 16 + fr;     // [0,512)
        float bv_ = bias[c];
        int h = c >> 6, dk = c & 63;
        #pragma unroll
        for (int m = 0; m < 4; ++m) {
            #pragma unroll
            for (int i = 0; i < 4; ++i) {
                int r = wr * 64 + m * 16 + rbase + i;
                if (r < rows) {
                    int tok = stok[r];
                    int b = tok >> 9, s = tok & 511;
                    outp[((size_t)((b * NH + h) * NS + s) << 6) + dk] =
                        f2bf((acc[m][n][i] + bv_) * qscale);
                }
            }
        }
    }
}

// ---------------- V transpose: vb [bh][s][dk] -> vtb [bh][dk][s] ----------------
__global__ __launch_bounds__(256) void transp_v(const u16* __restrict__ vb, u16* __restrict__ vtb)
{
    int bh = blockIdx.y, s0 = blockIdx.x * 64;
    __shared__ __align__(16) u16 t[64][72];
    int tid = threadIdx.x;
    const u16* src = vb + ((size_t)bh << 15) + ((size_t)s0 << 6);
    #pragma unroll
    for (int it = 0; it < 2; ++it) {
        int idx = it * 256 + tid;
        int s = idx & 63, c = idx >> 6;
        short8 v = *reinterpret_cast<const short8*>(src + ((size_t)s << 6) + c * 8);
        #pragma unroll
        for (int j = 0; j < 8; ++j) t[c * 8 + j][s] = ((const u16*)&v)[j];
    }
    __syncthreads();
    u16* dst = vtb + ((size_t)bh << 15) + s0;
    #pragma unroll
    for (int it = 0; it < 2; ++it) {
        int idx = it * 256 + tid;
        int dk = idx >> 3, c = idx & 7;
        short8 v = *reinterpret_cast<const short8*>(&t[dk][c * 8]);
        *reinterpret_cast<short8*>(dst + (size_t)dk * NS + c * 8) = v;
    }
}

// ---------------- MFMA flash attention, swapped-QK^T wave-parallel softmax ----------------
__global__ __launch_bounds__(256) void attn_mfma(
    const u16* __restrict__ qb, const u16* __restrict__ kbf, const u16* __restrict__ vtb,
    const u64* __restrict__ maskb, u16* __restrict__ attb)
{
    int work = (blockIdx.x & 7) * 128 + (blockIdx.x >> 3);  // XCD swizzle: all q-tiles of a bh on one XCD
    int bh = work >> 3, jq = work & 7;
    int b = bh >> 3, h = bh & 7;
    int q0 = jq * 64;
    int tid = threadIdx.x, lane = tid & 63, w = tid >> 6;
    int ln15 = lane & 15, g = lane >> 4;

    __shared__ __align__(16) u16 sK[64 * 64];    // [key][dk], XOR-swizzled
    __shared__ __align__(16) u16 sVt[64 * 64];   // [dk][key], XOR-swizzled
    __shared__ __align__(16) u16 sP[4 * 16 * 68];// per-wave [q][key], stride 68 u16

    // Q fragment (B-operand now): B[col=q=ln15][k=g*8..], pre-scaled by SCALE*log2e
    const u16* Qg = qb + ((size_t)(bh * NS + q0 + w * 16 + ln15) << 6);
    short8 aq0 = *reinterpret_cast<const short8*>(Qg + g * 8);
    short8 aq1 = *reinterpret_cast<const short8*>(Qg + 32 + g * 8);

    const u16* Kg = kbf + ((size_t)bh << 15);    // [s][dk]
    const u16* Vtg = vtb + ((size_t)bh << 15);   // [dk][s]
    int srow = tid >> 3, schunk = tid & 7;

    // per-lane softmax state for q = q0 + w*16 + ln15
    const u64* Mq = maskb + ((size_t)((b << 9) + q0 + w * 16 + ln15)) * 8;
    float mrun = -3.0e38f, lrun = 0.f;
    f32x4 acc_o[4] = {};

    short8 kpre0 = *reinterpret_cast<const short8*>(Kg + ((size_t)srow << 6) + schunk * 8);
    short8 kpre1 = *reinterpret_cast<const short8*>(Kg + ((size_t)(srow + 32) << 6) + schunk * 8);
    short8 vpre0 = *reinterpret_cast<const short8*>(Vtg + (size_t)srow * NS + schunk * 8);
    short8 vpre1 = *reinterpret_cast<const short8*>(Vtg + (size_t)(srow + 32) * NS + schunk * 8);

    char* sPw = (char*)sP + w * 16 * 136;        // this wave's private P region

    for (int j = 0; j < 8; ++j) {
        __syncthreads();
        {
            int r2 = srow + 32;
            *reinterpret_cast<short8*>((char*)sK  + srow * 128 + ((schunk * 16) ^ ((srow & 7) << 4))) = kpre0;
            *reinterpret_cast<short8*>((char*)sK  + r2   * 128 + ((schunk * 16) ^ ((r2   & 7) << 4))) = kpre1;
            *reinterpret_cast<short8*>((char*)sVt + srow * 128 + ((schunk * 16) ^ ((srow & 7) << 4))) = vpre0;
            *reinterpret_cast<short8*>((char*)sVt + r2   * 128 + ((schunk * 16) ^ ((r2   & 7) << 4))) = vpre1;
        }
        if (j < 7) {
            int j1 = j + 1;
            kpre0 = *reinterpret_cast<const short8*>(Kg + ((size_t)(j1 * 64 + srow) << 6) + schunk * 8);
            kpre1 = *reinterpret_cast<const short8*>(Kg + ((size_t)(j1 * 64 + srow + 32) << 6) + schunk * 8);
            vpre0 = *reinterpret_cast<const short8*>(Vtg + (size_t)srow * NS + j1 * 64 + schunk * 8);
            vpre1 = *reinterpret_cast<const short8*>(Vtg + (size_t)(srow + 32) * NS + j1 * 64 + schunk * 8);
        }
        __syncthreads();

        // swapped QK^T: D[key][q]; lane holds S[key = n*16 + g*4 + r][q = ln15]
        f32x4 accs[4] = {};
        #pragma unroll
        for (int ks = 0; ks < 2; ++ks) {
            short8 bq_ = ks ? aq1 : aq0;
            #pragma unroll
            for (int n = 0; n < 4; ++n) {
                int row = n * 16 + ln15;
                short8 kfrag = *reinterpret_cast<const short8*>(
                    (char*)sK + row * 128 + (((ks * 64) + g * 16) ^ ((row & 7) << 4)));
                accs[n] = __builtin_amdgcn_mfma_f32_16x16x32_bf16(kfrag, bq_, accs[n], 0, 0, 0);
            }
        }

        // wave-parallel online softmax: one q per lane, 16 scores in-register
        u64 mw = Mq[j];
        float sv[4][4];
        float mx = -3.0e38f;
        #pragma unroll
        for (int n = 0; n < 4; ++n) {
            u32 b4 = (u32)(mw >> (n * 16 + g * 4)) & 15u;
            #pragma unroll
            for (int r = 0; r < 4; ++r) {
                float s = (b4 >> r) & 1u ? accs[n][r] : -1.0e9f;
                sv[n][r] = s;
                mx = fmaxf(mx, s);
            }
        }
        mx = fmaxf(mx, __shfl_xor(mx, 16));
        mx = fmaxf(mx, __shfl_xor(mx, 32));      // full row max for q=ln15

        if (__any(mx > mrun + 8.f)) {            // defer-max (T13): rescale rarely
            float nm = fmaxf(mrun, mx);
            float sc = exp2f(mrun - nm);
            mrun = nm;
            lrun *= sc;
            #pragma unroll
            for (int i = 0; i < 4; ++i) {
                float si = __shfl(sc, g * 4 + i); // sc for q-row g*4+i (O-layout row)
                #pragma unroll
                for (int n2 = 0; n2 < 4; ++n2) acc_o[n2][i] *= si;
            }
        }

        float ps = 0.f;
        #pragma unroll
        for (int n = 0; n < 4; ++n) {
            float p0 = exp2f(sv[n][0] - mrun), p1 = exp2f(sv[n][1] - mrun);
            float p2 = exp2f(sv[n][2] - mrun), p3 = exp2f(sv[n][3] - mrun);
            ps += (p0 + p1) + (p2 + p3);
            // P[q=ln15][key = n*16 + g*4 + {0..3}] packed as 2 u32
            *reinterpret_cast<u32*>(sPw + ln15 * 136 + n * 32 + g * 8 + 0) = pk2(p0, p1);
            *reinterpret_cast<u32*>(sPw + ln15 * 136 + n * 32 + g * 8 + 4) = pk2(p2, p3);
        }
        ps += __shfl_xor(ps, 16);
        ps += __shfl_xor(ps, 32);                // full row sum
        lrun += ps;

        // PV: O[q][dk] += P @ V^T (sP same-wave; compiler orders lgkm)
        #pragma unroll
        for (int ks = 0; ks < 2; ++ks) {
            short8 ap = *reinterpret_cast<const short8*>(sPw + ln15 * 136 + ks * 64 + g * 16);
            #pragma unroll
            for (int n2 = 0; n2 < 4; ++n2) {
                int row = n2 * 16 + ln15;
                short8 vfrag = *reinterpret_cast<const short8*>(
                    (char*)sVt + row * 128 + (((ks * 64) + g * 16) ^ ((row & 7) << 4)));
                acc_o[n2] = __builtin_amdgcn_mfma_f32_16x16x32_bf16(ap, vfrag, acc_o[n2], 0, 0, 0);
            }
        }
    }

    // epilogue: per-lane l is already the full row sum for q=ln15
    float linv = 1.f / lrun;
    #pragma unroll
    for (int i = 0; i < 4; ++i) {
        float li = __shfl(linv, g * 4 + i);
        int q = q0 + w * 16 + g * 4 + i;
        #pragma unroll
        for (int n2 = 0; n2 < 4; ++n2) {
            attb[((size_t)((b << 9) + q) << 9) + (h << 6) + n2 * 16 + ln15] =
                f2bf(acc_o[n2][i] * li);
        }
    }
}

// ---------------- grouped out-proj GEMM + bias + residual; LDS dbuf + counted vmcnt ----------------
__global__ __launch_bounds__(256) void out_gemm(
    const u16* __restrict__ attb, const u16* __restrict__ Wat, const float* __restrict__ ba,
    const int* __restrict__ perm, const int* __restrict__ typeoff,
    const int* __restrict__ tile_type, const int* __restrict__ tile_row0, const int* __restrict__ ntiles,
    const float* __restrict__ x, float* __restrict__ hbuf)
{
    int work = (blockIdx.x & 7) * 36 + (blockIdx.x >> 3);   // XCD swizzle (288 = 8*36)
    int tile = work >> 2;
    if (tile >= *ntiles) return;
    int t = tile_type[tile];
    int row0 = tile_row0[tile];
    int rows = typeoff[t + 1] - row0; if (rows > BM) rows = BM;
    int col0 = (work & 3) * BN;
    const u16* W = Wat + ((size_t)t << 18);
    const float* bias = ba + (t << 9);

    __shared__ __align__(16) u16 As[2][BM][BKK];
    __shared__ __align__(16) u16 Bs[2][BM][BKK];
    __shared__ int stok[BM];

    int tid = threadIdx.x;
    if (tid < BM) stok[tid] = perm[row0 + (tid < rows ? tid : 0)];
    __syncthreads();

    int lane = tid & 63, w = tid >> 6;
    int wr = w >> 1, wc = w & 1;
    int fr = lane & 15, g = lane >> 4;

    int lrow = lane >> 3;
    int schunk = (lane & 7) ^ lrow;
    int tokA[4];
    #pragma unroll
    for (int k = 0; k < 4; ++k) tokA[k] = stok[w * 32 + k * 8 + lrow];

    auto stage = [&](int buf, int k0) {
        #pragma unroll
        for (int k = 0; k < 4; ++k) {
            gload16(attb + (((size_t)tokA[k]) << 9) + k0 + schunk * 8, &As[buf][w * 32 + k * 8][0]);
            gload16(W + (((size_t)(col0 + w * 32 + k * 8 + lrow)) << 9) + k0 + schunk * 8,
                    &Bs[buf][w * 32 + k * 8][0]);
        }
    };

    f32x4 acc[4][4] = {};

    stage(0, 0);
    #pragma unroll
    for (int it = 0; it < 8; ++it) {
        int cur = it & 1;
        if (it < 7) {
            stage(cur ^ 1, (it + 1) * BKK);
            asm volatile("s_waitcnt vmcnt(8)" ::: "memory");
        } else {
            asm volatile("s_waitcnt vmcnt(0)" ::: "memory");
        }
        __builtin_amdgcn_s_barrier();

        const char* Ab = (const char*)As[cur];
        const char* Bb = (const char*)Bs[cur];
        #pragma unroll
        for (int ks = 0; ks < 2; ++ks) {
            short8 af[4], bfr[4];
            #pragma unroll
            for (int m = 0; m < 4; ++m) {
                int r = wr * 64 + m * 16 + fr;
                af[m] = *reinterpret_cast<const short8*>(Ab + r * 128 + (((ks * 4 + g) ^ (r & 7)) << 4));
            }
            #pragma unroll
            for (int n = 0; n < 4; ++n) {
                int r = wc * 64 + n * 16 + fr;
                bfr[n] = *reinterpret_cast<const short8*>(Bb + r * 128 + (((ks * 4 + g) ^ (r & 7)) << 4));
            }
            #pragma unroll
            for (int m = 0; m < 4; ++m)
                #pragma unroll
                for (int n = 0; n < 4; ++n)
                    acc[m][n] = __builtin_amdgcn_mfma_f32_16x16x32_bf16(af[m], bfr[n], acc[m][n], 0, 0, 0);
        }
        asm volatile("s_waitcnt lgkmcnt(0)" ::: "memory");
        __builtin_amdgcn_s_barrier();
    }

    int rbase = g << 2;
    #pragma unroll
    for (int n = 0; n < 4; ++n) {
        int c = col0 + wc * 64 + n * 16 + fr;
        float bv_ = bias[c];
        #pragma unroll
        for (int m = 0; m < 4; ++m) {
            #pragma unroll
            for (int i = 0; i < 4; ++i) {
                int r = wr * 64 + m * 16 + rbase + i;
                if (r < rows) {
                    int tok = stok[r];
                    size_t off = (size_t)tok * ND + c;
                    hbuf[off] = acc[m][n][i] + bv_ + x[off];
                }
            }
        }
    }
}

// ---------------- per-type LayerNorm ----------------
__global__ __launch_bounds__(256) void lnorm(
    const float* __restrict__ hbuf, const int* __restrict__ xty,
    const float* __restrict__ gamma, const float* __restrict__ beta, float* __restrict__ out)
{
    int row = blockIdx.x * 4 + (threadIdx.x >> 6);
    int lane = threadIdx.x & 63;
    const float4* h4 = reinterpret_cast<const float4*>(hbuf + (size_t)row * ND);
    float4 a = h4[lane * 2], b = h4[lane * 2 + 1];
    float sum = a.x + a.y + a.z + a.w + b.x + b.y + b.z + b.w;
    float sq = a.x * a.x + a.y * a.y + a.z * a.z + a.w * a.w
             + b.x * b.x + b.y * b.y + b.z * b.z + b.w * b.w;
    #pragma unroll
    for (int off = 32; off; off >>= 1) { sum += __shfl_xor(sum, off); sq += __shfl_xor(sq, off); }
    float mu = sum * (1.f / ND);
    float var = sq * (1.f / ND) - mu * mu;
    float is = rsqrtf(var + 1e-5f);
    int t = xty[row];
    const float4* g4 = reinterpret_cast<const float4*>(gamma + ((size_t)t << 9));
    const float4* be4 = reinterpret_cast<const float4*>(beta + ((size_t)t << 9));
    float4 g0 = g4[lane * 2], g1 = g4[lane * 2 + 1];
    float4 b0 = be4[lane * 2], b1 = be4[lane * 2 + 1];
    float4 o0, o1;
    o0.x = (a.x - mu) * is * g0.x + b0.x;
    o0.y = (a.y - mu) * is * g0.y + b0.y;
    o0.z = (a.z - mu) * is * g0.z + b0.z;
    o0.w = (a.w - mu) * is * g0.w + b0.w;
    o1.x = (b.x - mu) * is * g1.x + b1.x;
    o1.y = (b.y - mu) * is * g1.y + b1.y;
    o1.z = (b.z - mu) * is * g1.z + b1.z;
    o1.w = (b.w - mu) * is * g1.w + b1.w;
    float4* out4 = reinterpret_cast<float4*>(out + (size_t)row * ND);
    out4[lane * 2] = o0; out4[lane * 2 + 1] = o1;
}

extern "C" void kernel_launch(void* const* d_in, const int* in_sizes, int n_in,
                              void* d_out, int out_size, void* d_ws, size_t ws_size,
                              hipStream_t stream)
{
    const float* x     = (const float*)d_in[0];
    const int*   xty   = (const int*)d_in[1];
    const int*   mask  = (const int*)d_in[2];
    const float* Wq    = (const float*)d_in[3];
    const float* bq    = (const float*)d_in[4];
    const float* Wk    = (const float*)d_in[5];
    const float* bk    = (const float*)d_in[6];
    const float* Wv    = (const float*)d_in[7];
    const float* bv    = (const float*)d_in[8];
    const float* Wa    = (const float*)d_in[9];
    const float* ba    = (const float*)d_in[10];
    const float* gamma = (const float*)d_in[11];
    const float* beta  = (const float*)d_in[12];
    float* out = (float*)d_out;

    char* ws = (char*)d_ws;
    u16*   xb      = (u16*)(ws + 0);             //  8 MB
    u16*   Wqt     = (u16*)(ws + 8388608);       //  4 MB each
    u16*   Wkt     = (u16*)(ws + 12582912);
    u16*   Wvt     = (u16*)(ws + 16777216);
    u16*   Wat     = (u16*)(ws + 20971520);
    u16*   qb      = (u16*)(ws + 25165824);      //  8 MB (bf16, pre-scaled)
    u16*   kbf     = (u16*)(ws + 33554432);      //  8 MB
    u16*   vb      = (u16*)(ws + 41943040);      //  8 MB (V, [bh][s][dk])
    u16*   vtb     = (u16*)(ws + 50331648);      //  8 MB (V^T, [bh][dk][s])
    u16*   attb    = (u16*)(ws + 58720256);      //  8 MB
    float* hbuf    = (float*)(ws + 67108864);    // 16 MB
    u64*   maskb   = (u64*)(ws + 83886080);      // 512 KB
    int*   perm    = (int*)(ws + 84410368);      //  32 KB
    int*   typeoff = (int*)(ws + 84443136);
    int*   ttile   = (int*)(ws + 84443200);
    int*   trow    = (int*)(ws + 84443520);
    int*   ntiles  = (int*)(ws + 84443840);

    bucketize<<<dim3(1), dim3(256), 0, stream>>>(xty, perm, typeoff, ttile, trow, ntiles);
    cvt_x<<<dim3(4096), dim3(256), 0, stream>>>(x, xb);
    cvt_w<<<dim3(8, 8, 32), dim3(256), 0, stream>>>(Wq, Wk, Wv, Wa, Wqt, Wkt, Wvt, Wat);
    pack_mask<<<dim3(16384), dim3(256), 0, stream>>>(mask, maskb);
    qkv_gemm<<<dim3(864), dim3(256), 0, stream>>>(xb, Wqt, Wkt, Wvt, bq, bk, bv,
                                                  perm, typeoff, ttile, trow, ntiles, qb, kbf, vb);
    transp_v<<<dim3(8, 128), dim3(256), 0, stream>>>(vb, vtb);
    attn_mfma<<<dim3(1024), dim3(256), 0, stream>>>(qb, kbf, vtb, maskb, attb);
    out_gemm<<<dim3(288), dim3(256), 0, stream>>>(attb, Wat, ba,
                                                  perm, typeoff, ttile, trow, ntiles, x, hbuf);
    lnorm<<<dim3(2048), dim3(256), 0, stream>>>(hbuf, xty, gamma, beta, out);
}

// Round 5
// 251.129 us; speedup vs baseline: 3.8479x; 1.0786x over previous
//
#include <hip/hip_runtime.h>
#include <hip/hip_bf16.h>

typedef __attribute__((ext_vector_type(8))) short short8;
typedef __attribute__((ext_vector_type(4))) float f32x4;
typedef __attribute__((ext_vector_type(4))) unsigned short u16x4;
typedef unsigned short u16;
typedef unsigned int u32;
typedef unsigned long long u64;

#define NB 16
#define NS 512
#define ND 512
#define NH 8
#define NT 8
#define NDK 64
#define NN (NB*NS)
#define SCALE_LOG2E 0.18033688011112042f   // (1/sqrt(64)) * log2(e)
#define BM 128
#define BN 128
#define BKK 64

__device__ __forceinline__ u16 f2bf(float f) {
    __hip_bfloat16 h = __float2bfloat16(f);
    return *reinterpret_cast<u16*>(&h);
}
__device__ __forceinline__ u32 pk2(float lo, float hi) {
    return (u32)f2bf(lo) | ((u32)f2bf(hi) << 16);
}

typedef const __attribute__((address_space(1))) void* gas_t;
typedef __attribute__((address_space(3))) void* las_t;

__device__ __forceinline__ void gload16(const void* gsrc, void* ldst) {
    __builtin_amdgcn_global_load_lds((gas_t)gsrc, (las_t)ldst, 16, 0, 0);
}

// ================= fused preprocessing =================
// blocks [0,4096): cvt_x ; [4096,6144): cvt_w ; [6144,7168): pack_mask (16 chunks each)
// [7168,7232): per-slice type count (64 slices x 128 tokens)
__global__ __launch_bounds__(256) void pre_all(
    const float* __restrict__ x, const int* __restrict__ xty, const int* __restrict__ mask,
    const float* __restrict__ Wq, const float* __restrict__ Wk,
    const float* __restrict__ Wv, const float* __restrict__ Wa,
    u16* __restrict__ xb,
    u16* __restrict__ Wqt, u16* __restrict__ Wkt, u16* __restrict__ Wvt, u16* __restrict__ Wat,
    u64* __restrict__ maskb, int* __restrict__ gcnt, int* __restrict__ scnt)
{
    __shared__ __align__(16) float tile[64][68];
    __shared__ int cnt[NT];
    int bid = blockIdx.x, tid = threadIdx.x;

    if (bid < 4096) {                           // ---- cvt_x ----
        int i = bid * 256 + tid;
        float4 v = reinterpret_cast<const float4*>(x)[i];
        u16x4 o;
        o.x = f2bf(v.x); o.y = f2bf(v.y); o.z = f2bf(v.z); o.w = f2bf(v.w);
        reinterpret_cast<u16x4*>(xb)[i] = o;
    } else if (bid < 6144) {                    // ---- cvt_w (transpose+convert) ----
        int wid = bid - 4096;
        int bx = wid & 7, by = (wid >> 3) & 7, bz = wid >> 6;
        int arr = bz >> 3, t = bz & 7;
        const float* W = (arr == 0 ? Wq : arr == 1 ? Wk : arr == 2 ? Wv : Wa) + ((size_t)t << 18);
        u16* O = (arr == 0 ? Wqt : arr == 1 ? Wkt : arr == 2 ? Wvt : Wat) + ((size_t)t << 18);
        int d0 = bx * 64, h0 = by * 64;
        int tx = tid & 15, ty = tid >> 4;
        #pragma unroll
        for (int i = 0; i < 4; ++i) {
            int r = ty + i * 16;
            float4 v = *reinterpret_cast<const float4*>(&W[(size_t)(d0 + r) * ND + h0 + tx * 4]);
            *reinterpret_cast<float4*>(&tile[r][tx * 4]) = v;
        }
        __syncthreads();
        #pragma unroll
        for (int i = 0; i < 4; ++i) {
            int r = ty + i * 16;
            u16x4 o;
            o.x = f2bf(tile[tx * 4 + 0][r]);
            o.y = f2bf(tile[tx * 4 + 1][r]);
            o.z = f2bf(tile[tx * 4 + 2][r]);
            o.w = f2bf(tile[tx * 4 + 3][r]);
            *reinterpret_cast<u16x4*>(&O[(size_t)(h0 + r) * ND + d0 + tx * 4]) = o;
        }
    } else if (bid < 7168) {                    // ---- pack_mask, grid-stride 16 ----
        int base = (bid - 6144) * 16;
        #pragma unroll
        for (int c = 0; c < 16; ++c) {
            int i = (base + c) * 256 + tid;
            int v = mask[i];
            u64 bal = __ballot(v != 0);
            if ((tid & 63) == 0) maskb[i >> 6] = bal;
        }
    } else {                                    // ---- type count, slice s ----
        int s = bid - 7168;
        if (tid < NT) cnt[tid] = 0;
        __syncthreads();
        if (tid < 128) atomicAdd(&cnt[xty[s * 128 + tid]], 1);
        __syncthreads();
        if (tid < NT) {
            scnt[s * 8 + tid] = cnt[tid];
            atomicAdd(&gcnt[tid], cnt[tid]);
        }
    }
}

// ================= scatter: build perm / typeoff / tile list =================
__global__ __launch_bounds__(256) void scatter_k(
    const int* __restrict__ xty, const int* __restrict__ gcnt, const int* __restrict__ scnt,
    int* __restrict__ perm, int* __restrict__ typeoff,
    int* __restrict__ tile_type, int* __restrict__ tile_row0, int* __restrict__ ntiles)
{
    __shared__ int base[NT];
    int s = blockIdx.x, tid = threadIdx.x;
    if (tid < NT) {                              // typeoff[t] = prefix of gcnt
        int off = 0;
        for (int tt = 0; tt < tid; ++tt) off += gcnt[tt];
        base[tid] = off;
    }
    __syncthreads();
    {                                            // += sum of earlier slices' counts (parallel)
        int t = tid & 7;
        for (int ss = tid >> 3; ss < s; ss += 32) atomicAdd(&base[t], scnt[ss * 8 + t]);
    }
    __syncthreads();
    if (tid < 128) {
        int n = s * 128 + tid;
        int t = xty[n];
        int p = atomicAdd(&base[t], 1);
        perm[p] = n;
    }
    if (s == 0 && tid == 0) {                    // tile list (deterministic, from totals)
        int acc = 0, nt = 0;
        for (int t = 0; t < NT; ++t) {
            typeoff[t] = acc;
            int c = gcnt[t];
            for (int r = 0; r < c; r += BM) { tile_type[nt] = t; tile_row0[nt] = acc + r; ++nt; }
            acc += c;
        }
        typeoff[NT] = acc;
        *ntiles = nt;
    }
}

// ================= grouped GEMM qkv: LDS dbuf + counted vmcnt + LDS-coalesced epilogue =================
__global__ __launch_bounds__(256) void qkv_gemm(
    const u16* __restrict__ xb,
    const u16* __restrict__ Wqt, const u16* __restrict__ Wkt, const u16* __restrict__ Wvt,
    const float* __restrict__ bq, const float* __restrict__ bk, const float* __restrict__ bv,
    const int* __restrict__ perm, const int* __restrict__ typeoff,
    const int* __restrict__ tile_type, const int* __restrict__ tile_row0, const int* __restrict__ ntiles,
    u16* __restrict__ qb, u16* __restrict__ kbf, u16* __restrict__ vb)
{
    int work = (blockIdx.x & 7) * 108 + (blockIdx.x >> 3);  // XCD swizzle (864 = 8*108)
    int tile = work / 12, pc = work % 12;
    if (tile >= *ntiles) return;
    int t = tile_type[tile];
    int row0 = tile_row0[tile];
    int rows = typeoff[t + 1] - row0; if (rows > BM) rows = BM;
    int proj = pc >> 2;
    int col0 = (pc & 3) * BN;
    const u16* W = (proj == 0 ? Wqt : proj == 1 ? Wkt : Wvt) + ((size_t)t << 18);
    const float* bias = (proj == 0 ? bq : proj == 1 ? bk : bv) + (t << 9);
    u16* outp = proj == 0 ? qb : proj == 1 ? kbf : vb;
    float qscale = proj == 0 ? SCALE_LOG2E : 1.f;

    __shared__ __align__(16) u16 smem[2][2][BM][BKK];   // [A/B][buf][][] = 64 KB
    __shared__ int stok[BM];
    auto As = smem[0]; auto Bs = smem[1];

    int tid = threadIdx.x;
    if (tid < BM) stok[tid] = perm[row0 + (tid < rows ? tid : 0)];
    __syncthreads();

    int lane = tid & 63, w = tid >> 6;
    int wr = w >> 1, wc = w & 1;
    int fr = lane & 15, g = lane >> 4;

    int lrow = lane >> 3;
    int schunk = (lane & 7) ^ lrow;             // pre-swizzled source chunk (16B units)
    int tokA[4];
    #pragma unroll
    for (int k = 0; k < 4; ++k) tokA[k] = stok[w * 32 + k * 8 + lrow];

    auto stage = [&](int buf, int k0) {
        #pragma unroll
        for (int k = 0; k < 4; ++k) {
            gload16(xb + (((size_t)tokA[k]) << 9) + k0 + schunk * 8, &As[buf][w * 32 + k * 8][0]);
            gload16(W + (((size_t)(col0 + w * 32 + k * 8 + lrow)) << 9) + k0 + schunk * 8,
                    &Bs[buf][w * 32 + k * 8][0]);
        }
    };

    f32x4 acc[4][4] = {};

    stage(0, 0);
    #pragma unroll
    for (int it = 0; it < 8; ++it) {
        int cur = it & 1;
        if (it < 7) {
            stage(cur ^ 1, (it + 1) * BKK);
            asm volatile("s_waitcnt vmcnt(8)" ::: "memory");   // cur's 8 loads done; next 8 in flight
        } else {
            asm volatile("s_waitcnt vmcnt(0)" ::: "memory");
        }
        __builtin_amdgcn_s_barrier();

        const char* Ab = (const char*)As[cur];
        const char* Bb = (const char*)Bs[cur];
        #pragma unroll
        for (int ks = 0; ks < 2; ++ks) {
            short8 af[4], bfr[4];
            #pragma unroll
            for (int m = 0; m < 4; ++m) {
                int r = wr * 64 + m * 16 + fr;
                af[m] = *reinterpret_cast<const short8*>(Ab + r * 128 + (((ks * 4 + g) ^ (r & 7)) << 4));
            }
            #pragma unroll
            for (int n = 0; n < 4; ++n) {
                int r = wc * 64 + n * 16 + fr;
                bfr[n] = *reinterpret_cast<const short8*>(Bb + r * 128 + (((ks * 4 + g) ^ (r & 7)) << 4));
            }
            #pragma unroll
            for (int m = 0; m < 4; ++m)
                #pragma unroll
                for (int n = 0; n < 4; ++n)
                    acc[m][n] = __builtin_amdgcn_mfma_f32_16x16x32_bf16(af[m], bfr[n], acc[m][n], 0, 0, 0);
        }
        asm volatile("s_waitcnt lgkmcnt(0)" ::: "memory");     // all LDS reads done before re-stage
        __builtin_amdgcn_s_barrier();
    }

    // epilogue: stage tile in LDS (reuse smem), store full-line coalesced per token
    u16 (*sT)[136] = reinterpret_cast<u16 (*)[136]>(&smem[0][0][0][0]);  // 128x136 u16 = 34.8 KB
    #pragma unroll
    for (int n = 0; n < 4; ++n) {
        int col = wc * 64 + n * 16 + fr;
        float bv_ = bias[col0 + col];
        #pragma unroll
        for (int m = 0; m < 4; ++m)
            #pragma unroll
            for (int i = 0; i < 4; ++i)
                sT[wr * 64 + m * 16 + g * 4 + i][col] = f2bf((acc[m][n][i] + bv_) * qscale);
    }
    __syncthreads();
    int r = tid >> 1, half = tid & 1;
    if (r < rows) {
        int tok = stok[r], b = tok >> 9, s = tok & 511;
        int h = (col0 >> 6) + half;
        u16* dst = outp + ((size_t)((b * NH + h) * NS + s) << 6);
        #pragma unroll
        for (int j = 0; j < 8; ++j)
            *reinterpret_cast<short8*>(dst + j * 8) =
                *reinterpret_cast<const short8*>(&sT[r][half * 64 + j * 8]);
    }
}

// ================= V transpose: vb [bh][s][dk] -> vtb [bh][dk][s] =================
__global__ __launch_bounds__(256) void transp_v(const u16* __restrict__ vb, u16* __restrict__ vtb)
{
    int bh = blockIdx.y, s0 = blockIdx.x * 64;
    __shared__ __align__(16) u16 t[64][72];
    int tid = threadIdx.x;
    const u16* src = vb + ((size_t)bh << 15) + ((size_t)s0 << 6);
    #pragma unroll
    for (int it = 0; it < 2; ++it) {
        int idx = it * 256 + tid;
        int s = idx & 63, c = idx >> 6;
        short8 v = *reinterpret_cast<const short8*>(src + ((size_t)s << 6) + c * 8);
        #pragma unroll
        for (int j = 0; j < 8; ++j) t[c * 8 + j][s] = ((const u16*)&v)[j];
    }
    __syncthreads();
    u16* dst = vtb + ((size_t)bh << 15) + s0;
    #pragma unroll
    for (int it = 0; it < 2; ++it) {
        int idx = it * 256 + tid;
        int dk = idx >> 3, c = idx & 7;
        short8 v = *reinterpret_cast<const short8*>(&t[dk][c * 8]);
        *reinterpret_cast<short8*>(dst + (size_t)dk * NS + c * 8) = v;
    }
}

// ================= MFMA flash attention, swapped-QK^T wave-parallel softmax =================
__global__ __launch_bounds__(256) void attn_mfma(
    const u16* __restrict__ qb, const u16* __restrict__ kbf, const u16* __restrict__ vtb,
    const u64* __restrict__ maskb, u16* __restrict__ attb)
{
    int work = (blockIdx.x & 7) * 128 + (blockIdx.x >> 3);  // XCD swizzle: bh-locality per XCD
    int bh = work >> 3, jq = work & 7;
    int b = bh >> 3, h = bh & 7;
    int q0 = jq * 64;
    int tid = threadIdx.x, lane = tid & 63, w = tid >> 6;
    int ln15 = lane & 15, g = lane >> 4;

    __shared__ __align__(16) u16 sK[64 * 64];    // [key][dk], XOR-swizzled
    __shared__ __align__(16) u16 sVt[64 * 64];   // [dk][key], XOR-swizzled
    __shared__ __align__(16) u16 sP[4 * 16 * 68];// per-wave [q][key], stride 68 u16

    const u16* Qg = qb + ((size_t)(bh * NS + q0 + w * 16 + ln15) << 6);
    short8 aq0 = *reinterpret_cast<const short8*>(Qg + g * 8);
    short8 aq1 = *reinterpret_cast<const short8*>(Qg + 32 + g * 8);

    const u16* Kg = kbf + ((size_t)bh << 15);    // [s][dk]
    const u16* Vtg = vtb + ((size_t)bh << 15);   // [dk][s]
    int srow = tid >> 3, schunk = tid & 7;

    const u64* Mq = maskb + ((size_t)((b << 9) + q0 + w * 16 + ln15)) * 8;
    float mrun = -3.0e38f, lrun = 0.f;
    f32x4 acc_o[4] = {};

    short8 kpre0 = *reinterpret_cast<const short8*>(Kg + ((size_t)srow << 6) + schunk * 8);
    short8 kpre1 = *reinterpret_cast<const short8*>(Kg + ((size_t)(srow + 32) << 6) + schunk * 8);
    short8 vpre0 = *reinterpret_cast<const short8*>(Vtg + (size_t)srow * NS + schunk * 8);
    short8 vpre1 = *reinterpret_cast<const short8*>(Vtg + (size_t)(srow + 32) * NS + schunk * 8);

    char* sPw = (char*)sP + w * 16 * 136;        // this wave's private P region

    for (int j = 0; j < 8; ++j) {
        __syncthreads();
        {
            int r2 = srow + 32;
            *reinterpret_cast<short8*>((char*)sK  + srow * 128 + ((schunk * 16) ^ ((srow & 7) << 4))) = kpre0;
            *reinterpret_cast<short8*>((char*)sK  + r2   * 128 + ((schunk * 16) ^ ((r2   & 7) << 4))) = kpre1;
            *reinterpret_cast<short8*>((char*)sVt + srow * 128 + ((schunk * 16) ^ ((srow & 7) << 4))) = vpre0;
            *reinterpret_cast<short8*>((char*)sVt + r2   * 128 + ((schunk * 16) ^ ((r2   & 7) << 4))) = vpre1;
        }
        if (j < 7) {
            int j1 = j + 1;
            kpre0 = *reinterpret_cast<const short8*>(Kg + ((size_t)(j1 * 64 + srow) << 6) + schunk * 8);
            kpre1 = *reinterpret_cast<const short8*>(Kg + ((size_t)(j1 * 64 + srow + 32) << 6) + schunk * 8);
            vpre0 = *reinterpret_cast<const short8*>(Vtg + (size_t)srow * NS + j1 * 64 + schunk * 8);
            vpre1 = *reinterpret_cast<const short8*>(Vtg + (size_t)(srow + 32) * NS + j1 * 64 + schunk * 8);
        }
        __syncthreads();

        // swapped QK^T: lane holds S[key = n*16 + g*4 + r][q = ln15]
        f32x4 accs[4] = {};
        __builtin_amdgcn_s_setprio(1);
        #pragma unroll
        for (int ks = 0; ks < 2; ++ks) {
            short8 bq_ = ks ? aq1 : aq0;
            #pragma unroll
            for (int n = 0; n < 4; ++n) {
                int row = n * 16 + ln15;
                short8 kfrag = *reinterpret_cast<const short8*>(
                    (char*)sK + row * 128 + (((ks * 64) + g * 16) ^ ((row & 7) << 4)));
                accs[n] = __builtin_amdgcn_mfma_f32_16x16x32_bf16(kfrag, bq_, accs[n], 0, 0, 0);
            }
        }
        __builtin_amdgcn_s_setprio(0);

        // wave-parallel online softmax: one q per lane
        u64 mw = Mq[j];
        float sv[4][4];
        float mx = -3.0e38f;
        #pragma unroll
        for (int n = 0; n < 4; ++n) {
            u32 b4 = (u32)(mw >> (n * 16 + g * 4)) & 15u;
            #pragma unroll
            for (int r = 0; r < 4; ++r) {
                float s = (b4 >> r) & 1u ? accs[n][r] : -1.0e9f;
                sv[n][r] = s;
                mx = fmaxf(mx, s);
            }
        }
        mx = fmaxf(mx, __shfl_xor(mx, 16));
        mx = fmaxf(mx, __shfl_xor(mx, 32));

        if (__any(mx > mrun + 8.f)) {            // defer-max (T13)
            float nm = fmaxf(mrun, mx);
            float sc = exp2f(mrun - nm);
            mrun = nm;
            lrun *= sc;
            #pragma unroll
            for (int i = 0; i < 4; ++i) {
                float si = __shfl(sc, g * 4 + i);
                #pragma unroll
                for (int n2 = 0; n2 < 4; ++n2) acc_o[n2][i] *= si;
            }
        }

        float ps = 0.f;
        #pragma unroll
        for (int n = 0; n < 4; ++n) {
            float p0 = exp2f(sv[n][0] - mrun), p1 = exp2f(sv[n][1] - mrun);
            float p2 = exp2f(sv[n][2] - mrun), p3 = exp2f(sv[n][3] - mrun);
            ps += (p0 + p1) + (p2 + p3);
            *reinterpret_cast<u32*>(sPw + ln15 * 136 + n * 32 + g * 8 + 0) = pk2(p0, p1);
            *reinterpret_cast<u32*>(sPw + ln15 * 136 + n * 32 + g * 8 + 4) = pk2(p2, p3);
        }
        ps += __shfl_xor(ps, 16);
        ps += __shfl_xor(ps, 32);
        lrun += ps;

        // PV: O[q][dk] += P @ V^T
        __builtin_amdgcn_s_setprio(1);
        #pragma unroll
        for (int ks = 0; ks < 2; ++ks) {
            short8 ap = *reinterpret_cast<const short8*>(sPw + ln15 * 136 + ks * 64 + g * 16);
            #pragma unroll
            for (int n2 = 0; n2 < 4; ++n2) {
                int row = n2 * 16 + ln15;
                short8 vfrag = *reinterpret_cast<const short8*>(
                    (char*)sVt + row * 128 + (((ks * 64) + g * 16) ^ ((row & 7) << 4)));
                acc_o[n2] = __builtin_amdgcn_mfma_f32_16x16x32_bf16(ap, vfrag, acc_o[n2], 0, 0, 0);
            }
        }
        __builtin_amdgcn_s_setprio(0);
    }

    float linv = 1.f / lrun;
    #pragma unroll
    for (int i = 0; i < 4; ++i) {
        float li = __shfl(linv, g * 4 + i);
        int q = q0 + w * 16 + g * 4 + i;
        #pragma unroll
        for (int n2 = 0; n2 < 4; ++n2) {
            attb[((size_t)((b << 9) + q) << 9) + (h << 6) + n2 * 16 + ln15] =
                f2bf(acc_o[n2][i] * li);
        }
    }
}

// ================= grouped out-proj GEMM + bias + residual =================
__global__ __launch_bounds__(256) void out_gemm(
    const u16* __restrict__ attb, const u16* __restrict__ Wat, const float* __restrict__ ba,
    const int* __restrict__ perm, const int* __restrict__ typeoff,
    const int* __restrict__ tile_type, const int* __restrict__ tile_row0, const int* __restrict__ ntiles,
    const float* __restrict__ x, float* __restrict__ hbuf)
{
    int work = (blockIdx.x & 7) * 36 + (blockIdx.x >> 3);   // XCD swizzle (288 = 8*36)
    int tile = work >> 2;
    if (tile >= *ntiles) return;
    int t = tile_type[tile];
    int row0 = tile_row0[tile];
    int rows = typeoff[t + 1] - row0; if (rows > BM) rows = BM;
    int col0 = (work & 3) * BN;
    const u16* W = Wat + ((size_t)t << 18);
    const float* bias = ba + (t << 9);

    __shared__ __align__(16) u16 As[2][BM][BKK];
    __shared__ __align__(16) u16 Bs[2][BM][BKK];
    __shared__ int stok[BM];

    int tid = threadIdx.x;
    if (tid < BM) stok[tid] = perm[row0 + (tid < rows ? tid : 0)];
    __syncthreads();

    int lane = tid & 63, w = tid >> 6;
    int wr = w >> 1, wc = w & 1;
    int fr = lane & 15, g = lane >> 4;

    int lrow = lane >> 3;
    int schunk = (lane & 7) ^ lrow;
    int tokA[4];
    #pragma unroll
    for (int k = 0; k < 4; ++k) tokA[k] = stok[w * 32 + k * 8 + lrow];

    auto stage = [&](int buf, int k0) {
        #pragma unroll
        for (int k = 0; k < 4; ++k) {
            gload16(attb + (((size_t)tokA[k]) << 9) + k0 + schunk * 8, &As[buf][w * 32 + k * 8][0]);
            gload16(W + (((size_t)(col0 + w * 32 + k * 8 + lrow)) << 9) + k0 + schunk * 8,
                    &Bs[buf][w * 32 + k * 8][0]);
        }
    };

    f32x4 acc[4][4] = {};

    stage(0, 0);
    #pragma unroll
    for (int it = 0; it < 8; ++it) {
        int cur = it & 1;
        if (it < 7) {
            stage(cur ^ 1, (it + 1) * BKK);
            asm volatile("s_waitcnt vmcnt(8)" ::: "memory");
        } else {
            asm volatile("s_waitcnt vmcnt(0)" ::: "memory");
        }
        __builtin_amdgcn_s_barrier();

        const char* Ab = (const char*)As[cur];
        const char* Bb = (const char*)Bs[cur];
        #pragma unroll
        for (int ks = 0; ks < 2; ++ks) {
            short8 af[4], bfr[4];
            #pragma unroll
            for (int m = 0; m < 4; ++m) {
                int r = wr * 64 + m * 16 + fr;
                af[m] = *reinterpret_cast<const short8*>(Ab + r * 128 + (((ks * 4 + g) ^ (r & 7)) << 4));
            }
            #pragma unroll
            for (int n = 0; n < 4; ++n) {
                int r = wc * 64 + n * 16 + fr;
                bfr[n] = *reinterpret_cast<const short8*>(Bb + r * 128 + (((ks * 4 + g) ^ (r & 7)) << 4));
            }
            #pragma unroll
            for (int m = 0; m < 4; ++m)
                #pragma unroll
                for (int n = 0; n < 4; ++n)
                    acc[m][n] = __builtin_amdgcn_mfma_f32_16x16x32_bf16(af[m], bfr[n], acc[m][n], 0, 0, 0);
        }
        asm volatile("s_waitcnt lgkmcnt(0)" ::: "memory");
        __builtin_amdgcn_s_barrier();
    }

    int rbase = g << 2;
    #pragma unroll
    for (int n = 0; n < 4; ++n) {
        int c = col0 + wc * 64 + n * 16 + fr;
        float bv_ = bias[c];
        #pragma unroll
        for (int m = 0; m < 4; ++m) {
            #pragma unroll
            for (int i = 0; i < 4; ++i) {
                int r = wr * 64 + m * 16 + rbase + i;
                if (r < rows) {
                    int tok = stok[r];
                    size_t off = (size_t)tok * ND + c;
                    hbuf[off] = acc[m][n][i] + bv_ + x[off];
                }
            }
        }
    }
}

// ================= per-type LayerNorm =================
__global__ __launch_bounds__(256) void lnorm(
    const float* __restrict__ hbuf, const int* __restrict__ xty,
    const float* __restrict__ gamma, const float* __restrict__ beta, float* __restrict__ out)
{
    int row = blockIdx.x * 4 + (threadIdx.x >> 6);
    int lane = threadIdx.x & 63;
    const float4* h4 = reinterpret_cast<const float4*>(hbuf + (size_t)row * ND);
    float4 a = h4[lane * 2], b = h4[lane * 2 + 1];
    float sum = a.x + a.y + a.z + a.w + b.x + b.y + b.z + b.w;
    float sq = a.x * a.x + a.y * a.y + a.z * a.z + a.w * a.w
             + b.x * b.x + b.y * b.y + b.z * b.z + b.w * b.w;
    #pragma unroll
    for (int off = 32; off; off >>= 1) { sum += __shfl_xor(sum, off); sq += __shfl_xor(sq, off); }
    float mu = sum * (1.f / ND);
    float var = sq * (1.f / ND) - mu * mu;
    float is = rsqrtf(var + 1e-5f);
    int t = xty[row];
    const float4* g4 = reinterpret_cast<const float4*>(gamma + ((size_t)t << 9));
    const float4* be4 = reinterpret_cast<const float4*>(beta + ((size_t)t << 9));
    float4 g0 = g4[lane * 2], g1 = g4[lane * 2 + 1];
    float4 b0 = be4[lane * 2], b1 = be4[lane * 2 + 1];
    float4 o0, o1;
    o0.x = (a.x - mu) * is * g0.x + b0.x;
    o0.y = (a.y - mu) * is * g0.y + b0.y;
    o0.z = (a.z - mu) * is * g0.z + b0.z;
    o0.w = (a.w - mu) * is * g0.w + b0.w;
    o1.x = (b.x - mu) * is * g1.x + b1.x;
    o1.y = (b.y - mu) * is * g1.y + b1.y;
    o1.z = (b.z - mu) * is * g1.z + b1.z;
    o1.w = (b.w - mu) * is * g1.w + b1.w;
    float4* out4 = reinterpret_cast<float4*>(out + (size_t)row * ND);
    out4[lane * 2] = o0; out4[lane * 2 + 1] = o1;
}

extern "C" void kernel_launch(void* const* d_in, const int* in_sizes, int n_in,
                              void* d_out, int out_size, void* d_ws, size_t ws_size,
                              hipStream_t stream)
{
    const float* x     = (const float*)d_in[0];
    const int*   xty   = (const int*)d_in[1];
    const int*   mask  = (const int*)d_in[2];
    const float* Wq    = (const float*)d_in[3];
    const float* bq    = (const float*)d_in[4];
    const float* Wk    = (const float*)d_in[5];
    const float* bk    = (const float*)d_in[6];
    const float* Wv    = (const float*)d_in[7];
    const float* bv    = (const float*)d_in[8];
    const float* Wa    = (const float*)d_in[9];
    const float* ba    = (const float*)d_in[10];
    const float* gamma = (const float*)d_in[11];
    const float* beta  = (const float*)d_in[12];
    float* out = (float*)d_out;

    char* ws = (char*)d_ws;
    u16*   xb      = (u16*)(ws + 0);             //  8 MB
    u16*   Wqt     = (u16*)(ws + 8388608);       //  4 MB each
    u16*   Wkt     = (u16*)(ws + 12582912);
    u16*   Wvt     = (u16*)(ws + 16777216);
    u16*   Wat     = (u16*)(ws + 20971520);
    u16*   qb      = (u16*)(ws + 25165824);      //  8 MB (bf16, pre-scaled)
    u16*   kbf     = (u16*)(ws + 33554432);      //  8 MB
    u16*   vb      = (u16*)(ws + 41943040);      //  8 MB (V, [bh][s][dk])
    u16*   vtb     = (u16*)(ws + 50331648);      //  8 MB (V^T, [bh][dk][s])
    u16*   attb    = (u16*)(ws + 58720256);      //  8 MB
    float* hbuf    = (float*)(ws + 67108864);    // 16 MB
    u64*   maskb   = (u64*)(ws + 83886080);      // 512 KB
    int*   perm    = (int*)(ws + 84410368);      //  32 KB
    int*   typeoff = (int*)(ws + 84443136);
    int*   ttile   = (int*)(ws + 84443200);
    int*   trow    = (int*)(ws + 84443776);
    int*   ntiles  = (int*)(ws + 84444352);
    int*   gcnt    = (int*)(ws + 84444416);      // 8 ints
    int*   scnt    = (int*)(ws + 84444480);      // 64*8 ints

    hipMemsetAsync(gcnt, 0, 32, stream);
    pre_all<<<dim3(7232), dim3(256), 0, stream>>>(x, xty, mask, Wq, Wk, Wv, Wa,
                                                  xb, Wqt, Wkt, Wvt, Wat, maskb, gcnt, scnt);
    scatter_k<<<dim3(64), dim3(256), 0, stream>>>(xty, gcnt, scnt, perm, typeoff, ttile, trow, ntiles);
    qkv_gemm<<<dim3(864), dim3(256), 0, stream>>>(xb, Wqt, Wkt, Wvt, bq, bk, bv,
                                                  perm, typeoff, ttile, trow, ntiles, qb, kbf, vb);
    transp_v<<<dim3(8, 128), dim3(256), 0, stream>>>(vb, vtb);
    attn_mfma<<<dim3(1024), dim3(256), 0, stream>>>(qb, kbf, vtb, maskb, attb);
    out_gemm<<<dim3(288), dim3(256), 0, stream>>>(attb, Wat, ba,
                                                  perm, typeoff, ttile, trow, ntiles, x, hbuf);
    lnorm<<<dim3(2048), dim3(256), 0, stream>>>(hbuf, xty, gamma, beta, out);
}